// Round 6
// baseline (312.959 us; speedup 1.0000x reference)
//
#include <hip/hip_runtime.h>
#include <math.h>

#define NPT 2048
#define KNN 20

typedef const float* fp;
typedef __attribute__((ext_vector_type(4))) float f32x4;
typedef __attribute__((ext_vector_type(8))) short s16x8;

// round-to-nearest-even f32 -> bf16 bits (inputs are finite)
__device__ __forceinline__ ushort f2bf_rne(float v) {
    unsigned u = __float_as_uint(v);
    unsigned r = u + 0x7FFFu + ((u >> 16) & 1u);
    return (ushort)(r >> 16);
}

__device__ __forceinline__ s16x8 ldfrag(const ushort* p) {
    union { uint4 u; s16x8 s; } cv;
    cv.u = *reinterpret_cast<const uint4*>(p);
    return cv.s;
}

// ---------------------------------------------------------------------------
// k0: zero BN stats (512 floats) — capture-safe.
// ---------------------------------------------------------------------------
__global__ void k0_zero(float* stats) { stats[threadIdx.x] = 0.0f; }

// ---------------------------------------------------------------------------
// prep: transpose weights to f32 wT[i][o] so compute kernels read
//       lane-consecutive (coalesced) weight vectors.
// ---------------------------------------------------------------------------
__global__ void prep_w(fp wq, fp wk, fp wv, fp wm, fp w1, fp w2,
                       float* wqT, float* wkT, float* wvT, float* wmT,
                       float* w1T, float* w2T) {
    int t = blockIdx.x * 256 + threadIdx.x;
    if (t < 65536) {                        // 4 matrices of 128x128
        int which = t >> 14, e = t & 16383;
        int o = e >> 7, i = e & 127;        // e = o*128+i (coalesced read)
        fp src = which == 0 ? wq : which == 1 ? wk : which == 2 ? wv : wm;
        float* dst = which == 0 ? wqT : which == 1 ? wkT : which == 2 ? wvT : wmT;
        dst[i * 128 + o] = src[e];
    } else if (t < 131072) {                // w1 256x256
        int e = t - 65536; int o = e >> 8, i = e & 255;
        w1T[i * 256 + o] = w1[e];
    } else if (t < 163840) {                // w2 128x256
        int e = t - 131072; int o = e >> 8, i = e & 255;
        w2T[i * 128 + o] = w2[e];
    }
}

// ---------------------------------------------------------------------------
// k1: per 16 points — stage x, emit xx, q/k/v = Wx+b (f32 point-major), and
//     (full path) bf16 hi/lo split of x in MFMA FRAGMENT layout:
//     block pt=point/16, kk=chan/32: 512 ushorts; lane l = (p&15)|(((c>>3)&3)<<4),
//     byte j = c&7  -> a wave ldfrag is one contiguous 1KB load.
// ---------------------------------------------------------------------------
__global__ __launch_bounds__(256) void k1_qkv(
    fp xbf, const float* wqT, const float* wkT, const float* wvT,
    fp bq, fp bk, fp bv,
    float* qT, float* kT, float* vT, float* xx, ushort* xhiF, ushort* xloF) {
    __shared__ float xs[16][129];
    int t = threadIdx.x;
    int p0 = blockIdx.x * 16;
    int b = p0 >> 11, n0 = p0 & 2047;
    fp xb = xbf + (size_t)b * 128 * NPT;

    {   // stage: thread t loads 8 consecutive n of channel c
        int c = t >> 1, half = t & 1;
        float4 f0 = *reinterpret_cast<const float4*>(xb + (size_t)c * NPT + n0 + half * 8);
        float4 f1 = *reinterpret_cast<const float4*>(xb + (size_t)c * NPT + n0 + half * 8 + 4);
        xs[half * 8 + 0][c] = f0.x; xs[half * 8 + 1][c] = f0.y;
        xs[half * 8 + 2][c] = f0.z; xs[half * 8 + 3][c] = f0.w;
        xs[half * 8 + 4][c] = f1.x; xs[half * 8 + 5][c] = f1.y;
        xs[half * 8 + 6][c] = f1.z; xs[half * 8 + 7][c] = f1.w;
    }
    __syncthreads();

    if (t < 16) {
        float s = 0.f;
        for (int c = 0; c < 128; c++) { float v = xs[t][c]; s += v * v; }
        xx[p0 + t] = s;
    }

    if (xhiF) {                             // fragment-layout hi/lo split
        int pt = blockIdx.x;
        #pragma unroll
        for (int r = 0; r < 8; r++) {
            int e = t + 256 * r;
            int p = e >> 7, c = e & 127;
            float v   = xs[p][c];
            ushort hi = f2bf_rne(v);
            float vlo = v - __uint_as_float(((unsigned)hi) << 16);
            size_t off = ((size_t)pt * 4 + (c >> 5)) * 512
                       + (size_t)((((c >> 3) & 3) * 16 + p) * 8 + (c & 7));
            xhiF[off] = hi;
            xloF[off] = f2bf_rne(vlo);
        }
    }

    int o = t & 127, pg = t >> 7;
    float aq[8], ak[8], av[8];
    #pragma unroll
    for (int k = 0; k < 8; k++) { aq[k] = 0.f; ak[k] = 0.f; av[k] = 0.f; }
    for (int i = 0; i < 128; i++) {
        float wqv = wqT[i * 128 + o];       // coalesced: lanes consecutive o
        float wkv = wkT[i * 128 + o];
        float wvv = wvT[i * 128 + o];
        #pragma unroll
        for (int k = 0; k < 8; k++) {
            float xv = xs[pg * 8 + k][i];
            aq[k] += wqv * xv; ak[k] += wkv * xv; av[k] += wvv * xv;
        }
    }
    float bqv = bq[o], bkv = bk[o], bvv = bv[o];
    #pragma unroll
    for (int k = 0; k < 8; k++) {
        size_t row = (size_t)(p0 + pg * 8 + k) * 128 + o;
        qT[row] = aq[k] + bqv;
        kT[row] = ak[k] + bkv;
        vT[row] = av[k] + bvv;
    }
}

// ---------------------------------------------------------------------------
// k2a: key GEMM, one batch slab (2048 rows). Wave = 16 rows x 128 cols,
//      hi/lo bf16 MFMA (3 products), all operand loads contiguous 1KB.
//      key[rowl][col] = 2*G - xx[col]  (row-constant -xx[n] dropped: ordering
//      within a row is unchanged).
// ---------------------------------------------------------------------------
__global__ __launch_bounds__(256) void k2a_gemm(
    const ushort* xhiF, const ushort* xloF, const float* xx,
    float* key, int rowbase) {
    int t = threadIdx.x, wv = t >> 6, lane = t & 63;
    int s   = blockIdx.x * 4 + wv;          // strip 0..2047
    int rtl = s >> 4;                       // local row-tile 0..127
    int cs  = s & 15;                       // col strip 0..15
    int b   = rowbase >> 11;                // slab == batch
    int rt  = (rowbase >> 4) + rtl;         // global row-tile
    int ct0 = b * 128 + cs * 8;             // global col-tile base

    f32x4 acc[8];
    #pragma unroll
    for (int j = 0; j < 8; j++) acc[j] = (f32x4){0.f, 0.f, 0.f, 0.f};

    for (int kk = 0; kk < 4; kk++) {
        s16x8 ahi = ldfrag(xhiF + ((size_t)(rt * 4 + kk)) * 512 + lane * 8);
        s16x8 alo = ldfrag(xloF + ((size_t)(rt * 4 + kk)) * 512 + lane * 8);
        #pragma unroll
        for (int j = 0; j < 8; j++) {
            s16x8 bhi = ldfrag(xhiF + ((size_t)((ct0 + j) * 4 + kk)) * 512 + lane * 8);
            s16x8 blo = ldfrag(xloF + ((size_t)((ct0 + j) * 4 + kk)) * 512 + lane * 8);
            acc[j] = __builtin_amdgcn_mfma_f32_16x16x32_bf16(ahi, bhi, acc[j], 0, 0, 0);
            acc[j] = __builtin_amdgcn_mfma_f32_16x16x32_bf16(alo, bhi, acc[j], 0, 0, 0);
            acc[j] = __builtin_amdgcn_mfma_f32_16x16x32_bf16(ahi, blo, acc[j], 0, 0, 0);
        }
    }
    // C/D layout: col = lane&15, row = (lane>>4)*4 + reg
    int rl = (lane >> 4) * 4, cl = lane & 15;
    int growl = rtl * 16 + rl;              // slab-local row
    #pragma unroll
    for (int j = 0; j < 8; j++) {
        int gcol = (cs * 8 + j) * 16 + cl;  // within-batch col
        float xxv = xx[b * 2048 + gcol];
        #pragma unroll
        for (int r = 0; r < 4; r++)
            key[(size_t)(growl + r) * 2048 + gcol] = 2.0f * acc[j][r] - xxv;
    }
}

// ---------------------------------------------------------------------------
// k2b: per-row top-20 from key slab. Wave per row, register candidates.
// ---------------------------------------------------------------------------
#define MERGE(off) { float ov = __shfl_xor(bv, off); int oi = __shfl_xor(bi, off); \
                     if (ov > bv || (ov == bv && oi < bi)) { bv = ov; bi = oi; } }

__global__ __launch_bounds__(256) void k2b_topk(
    const float* key, int* idxbuf, int rowbase) {
    int t = threadIdx.x, wv = t >> 6, lane = t & 63;
    int rowl = blockIdx.x * 4 + wv;         // 0..2047
    const float4* kr = reinterpret_cast<const float4*>(key + (size_t)rowl * 2048);
    float rv[32];                           // slot sl=j*4+e -> col j*256+lane*4+e
    #pragma unroll
    for (int j = 0; j < 8; j++) {
        float4 v = kr[j * 64 + lane];
        rv[j * 4 + 0] = v.x; rv[j * 4 + 1] = v.y;
        rv[j * 4 + 2] = v.z; rv[j * 4 + 3] = v.w;
    }
    unsigned removed = 0u;
    for (int iter = 0; iter < KNN; iter++) {
        float bv = -3.4e38f; int bi = 0;
        #pragma unroll
        for (int sl = 0; sl < 32; sl++) {   // ascending col per lane: strict >
            bool live = ((removed >> sl) & 1u) == 0u;
            if (live && rv[sl] > bv) { bv = rv[sl]; bi = (sl >> 2) * 256 + lane * 4 + (sl & 3); }
        }
        MERGE(32) MERGE(16) MERGE(8) MERGE(4) MERGE(2) MERGE(1)
        bi &= 2047;                                          // defensive
        if (lane == 0) idxbuf[(size_t)(rowbase + rowl) * KNN + iter] = bi;
        if (((bi >> 2) & 63) == lane) removed |= 1u << ((bi >> 8) * 4 + (bi & 3));
    }
}

// ---------------------------------------------------------------------------
// k2 fallback (ws too small): round-4 fused VALU pd + top-20 (known-good).
// ---------------------------------------------------------------------------
__global__ __launch_bounds__(256) void k2_fused(
    fp xbf, const float* xx, int* idxbuf) {
    __shared__ float pds[4][2048];
    __shared__ float xnl[4][128];
    __shared__ float xxs[4];
    int t = threadIdx.x;
    int r0 = blockIdx.x * 4;
    int b = r0 >> 11, nloc = r0 & 2047;
    fp xb = xbf + (size_t)b * 128 * NPT;

    for (int rr = 0; rr < 2; rr++) {
        int row = rr * 2 + (t >> 7), c = t & 127;
        xnl[row][c] = xb[c * NPT + nloc + row];
    }
    if (t < 4) xxs[t] = xx[r0 + t];
    __syncthreads();

    float acc[4][8];
    #pragma unroll
    for (int r = 0; r < 4; r++)
        #pragma unroll
        for (int j = 0; j < 8; j++) acc[r][j] = 0.f;

    for (int c = 0; c < 128; c++) {
        float4 f0 = *reinterpret_cast<const float4*>(xb + (size_t)c * NPT + t * 8);
        float4 f1 = *reinterpret_cast<const float4*>(xb + (size_t)c * NPT + t * 8 + 4);
        float xc[8] = {f0.x, f0.y, f0.z, f0.w, f1.x, f1.y, f1.z, f1.w};
        float xn0 = xnl[0][c], xn1 = xnl[1][c], xn2 = xnl[2][c], xn3 = xnl[3][c];
        #pragma unroll
        for (int j = 0; j < 8; j++) {
            acc[0][j] += xn0 * xc[j];
            acc[1][j] += xn1 * xc[j];
            acc[2][j] += xn2 * xc[j];
            acc[3][j] += xn3 * xc[j];
        }
    }
    float4 xxa = *reinterpret_cast<const float4*>(xx + b * NPT + t * 8);
    float4 xxb = *reinterpret_cast<const float4*>(xx + b * NPT + t * 8 + 4);
    float xxm[8] = {xxa.x, xxa.y, xxa.z, xxa.w, xxb.x, xxb.y, xxb.z, xxb.w};
    #pragma unroll
    for (int r = 0; r < 4; r++)
        #pragma unroll
        for (int j = 0; j < 8; j++)
            pds[r][t * 8 + j] = 2.0f * acc[r][j] - xxs[r] - xxm[j];
    __syncthreads();

    int row = t >> 6, lane = t & 63;
    float rv[32];
    #pragma unroll
    for (int q = 0; q < 32; q++) rv[q] = pds[row][lane + (q << 6)];
    unsigned removed = 0;
    for (int iter = 0; iter < KNN; iter++) {
        float bv = -3.4e38f; int bi = 0;
        #pragma unroll
        for (int q = 0; q < 32; q++) {
            bool live = ((removed >> q) & 1u) == 0u;
            if (live && rv[q] > bv) { bv = rv[q]; bi = lane + (q << 6); }
        }
        MERGE(32) MERGE(16) MERGE(8) MERGE(4) MERGE(2) MERGE(1)
        bi &= 2047;
        if (lane == 0) idxbuf[(size_t)(r0 + row) * KNN + iter] = bi;
        if ((bi & 63) == lane) removed |= 1u << (bi >> 6);
    }
}

// ---------------------------------------------------------------------------
// k3: sparse mutual-KNN attention. 128 threads = one point, t = h*32 + d.
// ---------------------------------------------------------------------------
__global__ __launch_bounds__(128) void k3_attn(
    fp qT, fp kT, fp vT, const int* idxbuf, float* avT) {
    __shared__ float sbuf[KNN * 4];
    __shared__ int   mlist[KNN];
    int t = threadIdx.x;
    int p = blockIdx.x;
    int b = p >> 11, n = p & 2047;
    int h = t >> 5;
    float qv = qT[(size_t)p * 128 + t];

    int cnt = 0;
    for (int j = 0; j < KNN; j++) {
        int m = idxbuf[(size_t)p * KNN + j] & 2047;
        const int* mrow = idxbuf + (size_t)(b * NPT + m) * KNN;
        bool mut = false;
        for (int jj = 0; jj < KNN; jj++) mut = mut || (mrow[jj] == n);
        if (mut) {
            float prod = qv * kT[(size_t)(b * NPT + m) * 128 + t];
            prod += __shfl_xor(prod, 16);
            prod += __shfl_xor(prod, 8);
            prod += __shfl_xor(prod, 4);
            prod += __shfl_xor(prod, 2);
            prod += __shfl_xor(prod, 1);
            if ((t & 31) == 0) sbuf[cnt * 4 + h] = prod * 0.17677669529663687f;
            if (t == 0) mlist[cnt] = m;
            cnt++;
        }
    }
    __syncthreads();

    float mx = -3.4e38f;
    for (int j = 0; j < cnt; j++) mx = fmaxf(mx, sbuf[j * 4 + h]);
    float den = 0.f;
    for (int j = 0; j < cnt; j++) den += expf(sbuf[j * 4 + h] - mx);
    float inv = (cnt > 0) ? (1.0f / den) : 0.0f;
    float acc = 0.f;
    for (int j = 0; j < cnt; j++) {
        float pw = expf(sbuf[j * 4 + h] - mx) * inv;
        acc += pw * vT[(size_t)(b * NPT + mlist[j]) * 128 + t];
    }
    avT[(size_t)p * 128 + t] = acc;
}

// ---------------------------------------------------------------------------
// k4: avm = wm@av + bm; h = w1@[x; avm] + b1; BN partial sums.
// ---------------------------------------------------------------------------
__global__ __launch_bounds__(256) void k4_h(
    fp xbf, const float* avT, const float* wmT, fp bm,
    const float* w1T, fp b1, float* hbuf, float* stats) {
    __shared__ float avs[16][128];
    __shared__ float cvec[16][256];
    int t = threadIdx.x;
    int p0 = blockIdx.x * 16;
    int b = p0 >> 11, n0 = p0 & 2047;
    fp xb = xbf + (size_t)b * 128 * NPT;

    for (int r = 0; r < 8; r++) {
        int e = t + 256 * r;
        int p = e >> 7, c = e & 127;
        avs[p][c] = avT[(size_t)(p0 + p) * 128 + c];
    }
    {
        int c = t >> 1, half = t & 1;
        float4 f0 = *reinterpret_cast<const float4*>(xb + (size_t)c * NPT + n0 + half * 8);
        float4 f1 = *reinterpret_cast<const float4*>(xb + (size_t)c * NPT + n0 + half * 8 + 4);
        cvec[half * 8 + 0][c] = f0.x; cvec[half * 8 + 1][c] = f0.y;
        cvec[half * 8 + 2][c] = f0.z; cvec[half * 8 + 3][c] = f0.w;
        cvec[half * 8 + 4][c] = f1.x; cvec[half * 8 + 5][c] = f1.y;
        cvec[half * 8 + 6][c] = f1.z; cvec[half * 8 + 7][c] = f1.w;
    }
    __syncthreads();

    int o = t & 127, pg = t >> 7;
    float am[8];
    #pragma unroll
    for (int k = 0; k < 8; k++) am[k] = 0.f;
    for (int i = 0; i < 128; i++) {
        float w = wmT[i * 128 + o];         // coalesced
        #pragma unroll
        for (int k = 0; k < 8; k++) am[k] += w * avs[pg * 8 + k][i];
    }
    float bmv = bm[o];
    #pragma unroll
    for (int k = 0; k < 8; k++) cvec[pg * 8 + k][128 + o] = am[k] + bmv;
    __syncthreads();

    float hh[16];
    #pragma unroll
    for (int p = 0; p < 16; p++) hh[p] = 0.f;
    for (int i = 0; i < 256; i++) {
        float w = w1T[i * 256 + t];         // coalesced
        #pragma unroll
        for (int p = 0; p < 16; p++) hh[p] += w * cvec[p][i];
    }
    float b1v = b1[t];
    float s = 0.f, s2 = 0.f;
    for (int p = 0; p < 16; p++) {
        float v = hh[p] + b1v;
        hbuf[(size_t)(p0 + p) * 256 + t] = v;
        s += v; s2 += v * v;
    }
    atomicAdd(&stats[t], s);
    atomicAdd(&stats[256 + t], s2);
}

// ---------------------------------------------------------------------------
// k5: BN + ReLU + w2 conv + residual -> f32 out (B,C,N,1).
// ---------------------------------------------------------------------------
__global__ __launch_bounds__(256) void k5_out(
    const float* hbuf, const float* stats, fp gamma, fp beta,
    const float* w2T, fp b2, fp xbf, float* out) {
    __shared__ float hn[16][256];
    int t = threadIdx.x;
    int p0 = blockIdx.x * 16;
    int b = p0 >> 11, n0 = p0 & 2047;

    float mu  = stats[t] * (1.0f / 4096.0f);
    float var = stats[256 + t] * (1.0f / 4096.0f) - mu * mu;
    var = fmaxf(var, 0.0f);
    float a    = gamma[t] / sqrtf(var + 1e-5f);
    float cadd = beta[t] - mu * a;
    for (int r = 0; r < 16; r++) {
        float v = hbuf[(size_t)(p0 + r) * 256 + t] * a + cadd;
        hn[r][t] = fmaxf(v, 0.0f);
    }
    __syncthreads();

    int o = t & 127, pg = t >> 7;
    float acc[8];
    #pragma unroll
    for (int k = 0; k < 8; k++) acc[k] = 0.f;
    for (int i = 0; i < 256; i++) {
        float w = w2T[i * 128 + o];         // coalesced
        #pragma unroll
        for (int k = 0; k < 8; k++) acc[k] += w * hn[pg * 8 + k][i];
    }
    fp xb = xbf + (size_t)b * 128 * NPT;
    float4 x0 = *reinterpret_cast<const float4*>(xb + (size_t)o * NPT + n0 + pg * 8);
    float4 x1 = *reinterpret_cast<const float4*>(xb + (size_t)o * NPT + n0 + pg * 8 + 4);
    float xv[8] = {x0.x, x0.y, x0.z, x0.w, x1.x, x1.y, x1.z, x1.w};

    float b2v = b2[o];
    float4 o0, o1;
    o0.x = acc[0] + b2v + xv[0]; o0.y = acc[1] + b2v + xv[1];
    o0.z = acc[2] + b2v + xv[2]; o0.w = acc[3] + b2v + xv[3];
    o1.x = acc[4] + b2v + xv[4]; o1.y = acc[5] + b2v + xv[5];
    o1.z = acc[6] + b2v + xv[6]; o1.w = acc[7] + b2v + xv[7];
    size_t base = (size_t)b * 128 * NPT + (size_t)o * NPT + n0 + pg * 8;
    *reinterpret_cast<float4*>(out + base)     = o0;
    *reinterpret_cast<float4*>(out + base + 4) = o1;
}

// ---------------------------------------------------------------------------
// Workspace layout:
//   base region (always used, <= 9,390,080 B, known-safe):
//     0        qT 2MB [k1->k3]     <- hbuf 4MB (k4->k5) aliases qT+kT
//     2097152  kT 2MB
//     4194304  vT 2MB
//     6291456  avT 2MB [k3->k4]
//     8388608  xx 16KB
//     8404992  idxb 320KB
//     8732672  stats 2KB
//     8734720  wqT/wkT/wvT/wmT 4x64KB
//     8996864  w1T 256KB
//     9259008  w2T 128KB           (end 9390080)
//   full-path extras:
//     9390080  xhiF 1MB   [k1->k2a]
//     10438656 xloF 1MB
//     11487232 key 16MB   [k2a->k2b, reused per batch slab]
//   WS_FULL = 28264448
// ---------------------------------------------------------------------------
#define WS_FULL 28264448u

extern "C" void kernel_launch(void* const* d_in, const int* in_sizes, int n_in,
                              void* d_out, int out_size, void* d_ws, size_t ws_size,
                              hipStream_t stream) {
    fp desc1 = (fp)d_in[0];
    fp wq = (fp)d_in[1];  fp bq = (fp)d_in[2];
    fp wk = (fp)d_in[3];  fp bk = (fp)d_in[4];
    fp wv = (fp)d_in[5];  fp bv = (fp)d_in[6];
    fp wm = (fp)d_in[7];  fp bm = (fp)d_in[8];
    fp w1 = (fp)d_in[9];  fp b1 = (fp)d_in[10];
    fp gamma = (fp)d_in[11]; fp beta = (fp)d_in[12];
    fp w2 = (fp)d_in[13]; fp b2 = (fp)d_in[14];

    char* ws = (char*)d_ws;
    float*  qT    = (float*) (ws + 0);
    float*  kT    = (float*) (ws + 2097152);
    float*  vT    = (float*) (ws + 4194304);
    float*  avT   = (float*) (ws + 6291456);
    float*  xx    = (float*) (ws + 8388608);
    int*    idxb  = (int*)   (ws + 8404992);
    float*  stats = (float*) (ws + 8732672);
    float*  wqT   = (float*) (ws + 8734720);
    float*  wkT   = (float*) (ws + 8800256);
    float*  wvT   = (float*) (ws + 8865792);
    float*  wmT   = (float*) (ws + 8931328);
    float*  w1T   = (float*) (ws + 8996864);
    float*  w2T   = (float*) (ws + 9259008);
    ushort* xhiF  = (ushort*)(ws + 9390080);
    ushort* xloF  = (ushort*)(ws + 10438656);
    float*  key   = (float*) (ws + 11487232);
    float*  hbuf  = (float*) (ws + 0);       // aliases qT+kT (dead after k3)

    const bool full = (ws_size >= (size_t)WS_FULL);  // ws_size is constant:
                                                     // same path every call
    k0_zero<<<1, 512, 0, stream>>>(stats);
    prep_w<<<640, 256, 0, stream>>>(wq, wk, wv, wm, w1, w2,
                                    wqT, wkT, wvT, wmT, w1T, w2T);
    k1_qkv<<<256, 256, 0, stream>>>(desc1, wqT, wkT, wvT, bq, bk, bv,
                                    qT, kT, vT, xx,
                                    full ? xhiF : nullptr,
                                    full ? xloF : nullptr);
    if (full) {
        for (int s = 0; s < 2; s++) {       // per-batch slab, key reused
            k2a_gemm<<<512, 256, 0, stream>>>(xhiF, xloF, xx, key, s * 2048);
            k2b_topk<<<512, 256, 0, stream>>>(key, idxb, s * 2048);
        }
    } else {
        k2_fused<<<1024, 256, 0, stream>>>(desc1, xx, idxb);
    }
    k3_attn<<<4096, 128, 0, stream>>>(qT, kT, vT, idxb, avT);
    k4_h<<<256, 256, 0, stream>>>(desc1, avT, wmT, bm, w1T, b1, hbuf, stats);
    k5_out<<<256, 256, 0, stream>>>(hbuf, stats, gamma, beta, w2T, b2, desc1,
                                    (float*)d_out);
}

// Round 7
// 271.486 us; speedup vs baseline: 1.1528x; 1.1528x over previous
//
#include <hip/hip_runtime.h>
#include <math.h>

#define NPT 2048
#define KNN 20

typedef const float* fp;
typedef __attribute__((ext_vector_type(4))) float f32x4;
typedef __attribute__((ext_vector_type(8))) short s16x8;

// round-to-nearest-even f32 -> bf16 bits (inputs are finite)
__device__ __forceinline__ ushort f2bf_rne(float v) {
    unsigned u = __float_as_uint(v);
    unsigned r = u + 0x7FFFu + ((u >> 16) & 1u);
    return (ushort)(r >> 16);
}
__device__ __forceinline__ float bfbits2f(ushort h) {
    return __uint_as_float(((unsigned)h) << 16);
}
__device__ __forceinline__ s16x8 ldfrag(const ushort* p) {
    union { uint4 u; s16x8 s; } cv;
    cv.u = *reinterpret_cast<const uint4*>(p);
    return cv.s;
}

// ---------------------------------------------------------------------------
// prep_w: (a) bf16 hi/lo MFMA B-fragments for wq/wk/wv  (B[k][n] = W[n][k],
//         frag elem (tile nt,kk): lane l, j -> W[nt*16+(l&15)][kk*32+(l>>4)*8+j],
//         stored at (nt*4+kk)*512 + l*8 + j  — same addressing as x frags);
//         (b) f32 transposes wmT/w1T/w2T for k4/k5; (c) zero BN stats.
// ---------------------------------------------------------------------------
__global__ void prep_w(fp wq, fp wk, fp wv, fp wm, fp w1, fp w2,
                       float* wmT, float* w1T, float* w2T,
                       ushort* wqFhi, ushort* wqFlo, ushort* wkFhi, ushort* wkFlo,
                       ushort* wvFhi, ushort* wvFlo, float* stats) {
    int t = blockIdx.x * 256 + threadIdx.x;
    if (t < 49152) {                        // q/k/v fragments (3 x 16384)
        int which = t >> 14, e = t & 16383;
        int lane = (e >> 3) & 63, j = e & 7, kk = (e >> 9) & 3, nt = e >> 11;
        int n = nt * 16 + (lane & 15);
        int k = kk * 32 + (lane >> 4) * 8 + j;
        fp src = which == 0 ? wq : which == 1 ? wk : wv;
        float v = src[n * 128 + k];
        ushort hi = f2bf_rne(v);
        float lo = v - bfbits2f(hi);
        (which == 0 ? wqFhi : which == 1 ? wkFhi : wvFhi)[e] = hi;
        (which == 0 ? wqFlo : which == 1 ? wkFlo : wvFlo)[e] = f2bf_rne(lo);
    } else if (t < 65536) {                 // wm 128x128 transpose
        int e = t - 49152; int o = e >> 7, i = e & 127;
        wmT[i * 128 + o] = wm[e];
    } else if (t < 131072) {                // w1 256x256 transpose
        int e = t - 65536; int o = e >> 8, i = e & 255;
        w1T[i * 256 + o] = w1[e];
    } else if (t < 163840) {                // w2 128x256 transpose
        int e = t - 131072; int o = e >> 8, i = e & 255;
        w2T[i * 128 + o] = w2[e];
    } else if (t < 164352) {                // BN stats zero
        stats[t - 163840] = 0.0f;
    }
}

// ---------------------------------------------------------------------------
// k1a: fragify x (bf16 hi/lo, MFMA A layout) + xx (sum of squares).
//      Thread (p = t&15, g = t>>4) owns channels g*8..g*8+7 of point p:
//      frag offsets are 8 consecutive ushorts -> one uint4 store each.
// ---------------------------------------------------------------------------
__global__ __launch_bounds__(256) void k1a_frag(
    fp xbf, float* xx, ushort* xhiF, ushort* xloF) {
    __shared__ float xs[16][129];
    __shared__ float xpart[16][17];
    int t = threadIdx.x;
    int p0 = blockIdx.x * 16;
    int b = p0 >> 11, n0 = p0 & 2047;
    fp xb = xbf + (size_t)b * 128 * NPT;

    {   // stage: thread t loads 8 consecutive n of channel c
        int c = t >> 1, half = t & 1;
        float4 f0 = *reinterpret_cast<const float4*>(xb + (size_t)c * NPT + n0 + half * 8);
        float4 f1 = *reinterpret_cast<const float4*>(xb + (size_t)c * NPT + n0 + half * 8 + 4);
        xs[half * 8 + 0][c] = f0.x; xs[half * 8 + 1][c] = f0.y;
        xs[half * 8 + 2][c] = f0.z; xs[half * 8 + 3][c] = f0.w;
        xs[half * 8 + 4][c] = f1.x; xs[half * 8 + 5][c] = f1.y;
        xs[half * 8 + 6][c] = f1.z; xs[half * 8 + 7][c] = f1.w;
    }
    __syncthreads();

    int p = t & 15, g = t >> 4, c0 = g * 8;
    float f[8];
    #pragma unroll
    for (int j = 0; j < 8; j++) f[j] = xs[p][c0 + j];
    float ps = 0.f;
    #pragma unroll
    for (int j = 0; j < 8; j++) ps += f[j] * f[j];
    xpart[p][g] = ps;

    union { ushort u[8]; uint4 q; } H, L;
    #pragma unroll
    for (int j = 0; j < 8; j++) {
        ushort hi = f2bf_rne(f[j]);
        H.u[j] = hi;
        L.u[j] = f2bf_rne(f[j] - bfbits2f(hi));
    }
    size_t off = ((size_t)blockIdx.x * 4 + (c0 >> 5)) * 512
               + (size_t)(((((c0 >> 3) & 3) * 16) + p) * 8);
    *reinterpret_cast<uint4*>(xhiF + off) = H.q;
    *reinterpret_cast<uint4*>(xloF + off) = L.q;

    __syncthreads();
    if (t < 16) {
        float s = 0.f;
        #pragma unroll
        for (int gg = 0; gg < 16; gg++) s += xpart[t][gg];
        xx[p0 + t] = s;
    }
}

// ---------------------------------------------------------------------------
// k1b: q/k/v GEMM via MFMA (hi/lo split). Wave-task = 16 points x 64 chans of
//      one of {q,k,v}: 256 row-tiles x 2 halves x 3 mats = 1536 waves.
// ---------------------------------------------------------------------------
__global__ __launch_bounds__(256) void k1b_qkv(
    const ushort* xhiF, const ushort* xloF,
    const ushort* wqFhi, const ushort* wqFlo,
    const ushort* wkFhi, const ushort* wkFlo,
    const ushort* wvFhi, const ushort* wvFlo,
    fp bq, fp bk, fp bv, float* qT, float* kT, float* vT) {
    int t = threadIdx.x, wvi = t >> 6, lane = t & 63;
    int gw = blockIdx.x * 4 + wvi;          // 0..1535
    int rt = gw / 6, rem = gw - rt * 6;
    int mat = rem >> 1, hf = rem & 1;
    const ushort* whi = mat == 0 ? wqFhi : mat == 1 ? wkFhi : wvFhi;
    const ushort* wlo = mat == 0 ? wqFlo : mat == 1 ? wkFlo : wvFlo;
    fp bias   = mat == 0 ? bq : mat == 1 ? bk : bv;
    float* out = mat == 0 ? qT : mat == 1 ? kT : vT;

    f32x4 acc[4];
    #pragma unroll
    for (int j = 0; j < 4; j++) acc[j] = (f32x4){0.f, 0.f, 0.f, 0.f};

    for (int kk = 0; kk < 4; kk++) {
        s16x8 ahi = ldfrag(xhiF + ((size_t)(rt * 4 + kk)) * 512 + lane * 8);
        s16x8 alo = ldfrag(xloF + ((size_t)(rt * 4 + kk)) * 512 + lane * 8);
        #pragma unroll
        for (int j = 0; j < 4; j++) {
            int nt = hf * 4 + j;
            s16x8 bhi = ldfrag(whi + ((size_t)(nt * 4 + kk)) * 512 + lane * 8);
            s16x8 blo = ldfrag(wlo + ((size_t)(nt * 4 + kk)) * 512 + lane * 8);
            acc[j] = __builtin_amdgcn_mfma_f32_16x16x32_bf16(ahi, bhi, acc[j], 0, 0, 0);
            acc[j] = __builtin_amdgcn_mfma_f32_16x16x32_bf16(alo, bhi, acc[j], 0, 0, 0);
            acc[j] = __builtin_amdgcn_mfma_f32_16x16x32_bf16(ahi, blo, acc[j], 0, 0, 0);
        }
    }
    int cl = lane & 15, quad = lane >> 4, p0 = rt * 16;
    #pragma unroll
    for (int j = 0; j < 4; j++) {
        int o = hf * 64 + j * 16 + cl;
        float bvv = bias[o];
        #pragma unroll
        for (int r = 0; r < 4; r++)
            out[(size_t)(p0 + quad * 4 + r) * 128 + o] = acc[j][r] + bvv;
    }
}

// ---------------------------------------------------------------------------
// k2a: key GEMM, one batch slab. Wave = 16 rows x 64 cols (4 j-tiles):
//      4096 wave-tasks = 1024 blocks. key = 2*G - xx[col].
// ---------------------------------------------------------------------------
__global__ __launch_bounds__(256) void k2a_gemm(
    const ushort* xhiF, const ushort* xloF, const float* xx,
    float* key, int rowbase) {
    int t = threadIdx.x, wvi = t >> 6, lane = t & 63;
    int gw = blockIdx.x * 4 + wvi;          // 0..4095
    int rtl = gw >> 5;                      // row-tile 0..127
    int cs  = gw & 31;                      // col strip (64 cols) 0..31
    int b   = rowbase >> 11;
    int rt  = (rowbase >> 4) + rtl;

    f32x4 acc[4];
    #pragma unroll
    for (int j = 0; j < 4; j++) acc[j] = (f32x4){0.f, 0.f, 0.f, 0.f};

    for (int kk = 0; kk < 4; kk++) {
        s16x8 ahi = ldfrag(xhiF + ((size_t)(rt * 4 + kk)) * 512 + lane * 8);
        s16x8 alo = ldfrag(xloF + ((size_t)(rt * 4 + kk)) * 512 + lane * 8);
        #pragma unroll
        for (int j = 0; j < 4; j++) {
            int ct = b * 128 + cs * 4 + j;
            s16x8 bhi = ldfrag(xhiF + ((size_t)(ct * 4 + kk)) * 512 + lane * 8);
            s16x8 blo = ldfrag(xloF + ((size_t)(ct * 4 + kk)) * 512 + lane * 8);
            acc[j] = __builtin_amdgcn_mfma_f32_16x16x32_bf16(ahi, bhi, acc[j], 0, 0, 0);
            acc[j] = __builtin_amdgcn_mfma_f32_16x16x32_bf16(alo, bhi, acc[j], 0, 0, 0);
            acc[j] = __builtin_amdgcn_mfma_f32_16x16x32_bf16(ahi, blo, acc[j], 0, 0, 0);
        }
    }
    int cl = lane & 15, quad = lane >> 4;
    #pragma unroll
    for (int j = 0; j < 4; j++) {
        int col = cs * 64 + j * 16 + cl;    // slab-local col
        float xxv = xx[b * 2048 + col];
        #pragma unroll
        for (int r = 0; r < 4; r++)
            key[(size_t)(rtl * 16 + quad * 4 + r) * 2048 + col] = 2.0f * acc[j][r] - xxv;
    }
}

// ---------------------------------------------------------------------------
// k2b: per-row top-20 from key slab. Wave per row, register candidates.
// ---------------------------------------------------------------------------
#define MERGE(off) { float ov = __shfl_xor(bv, off); int oi = __shfl_xor(bi, off); \
                     if (ov > bv || (ov == bv && oi < bi)) { bv = ov; bi = oi; } }

__global__ __launch_bounds__(256) void k2b_topk(
    const float* key, int* idxbuf, int rowbase) {
    int t = threadIdx.x, wvi = t >> 6, lane = t & 63;
    int rowl = blockIdx.x * 4 + wvi;        // 0..2047
    const float4* kr = reinterpret_cast<const float4*>(key + (size_t)rowl * 2048);
    float rv[32];                           // slot sl=j*4+e -> col j*256+lane*4+e
    #pragma unroll
    for (int j = 0; j < 8; j++) {
        float4 v = kr[j * 64 + lane];
        rv[j * 4 + 0] = v.x; rv[j * 4 + 1] = v.y;
        rv[j * 4 + 2] = v.z; rv[j * 4 + 3] = v.w;
    }
    unsigned removed = 0u;
    for (int iter = 0; iter < KNN; iter++) {
        float bv = -3.4e38f; int bi = 0;
        #pragma unroll
        for (int sl = 0; sl < 32; sl++) {   // ascending col per lane: strict >
            bool live = ((removed >> sl) & 1u) == 0u;
            if (live && rv[sl] > bv) { bv = rv[sl]; bi = (sl >> 2) * 256 + lane * 4 + (sl & 3); }
        }
        MERGE(32) MERGE(16) MERGE(8) MERGE(4) MERGE(2) MERGE(1)
        bi &= 2047;                                          // defensive
        if (lane == 0) idxbuf[(size_t)(rowbase + rowl) * KNN + iter] = bi;
        if (((bi >> 2) & 63) == lane) removed |= 1u << ((bi >> 8) * 4 + (bi & 3));
    }
}

// ---------------------------------------------------------------------------
// k3: sparse mutual-KNN attention. 128 threads = one point, t = h*32 + d.
// ---------------------------------------------------------------------------
__global__ __launch_bounds__(128) void k3_attn(
    fp qT, fp kT, fp vT, const int* idxbuf, float* avT) {
    __shared__ float sbuf[KNN * 4];
    __shared__ int   mlist[KNN];
    int t = threadIdx.x;
    int p = blockIdx.x;
    int b = p >> 11, n = p & 2047;
    int h = t >> 5;
    float qv = qT[(size_t)p * 128 + t];

    int cnt = 0;
    for (int j = 0; j < KNN; j++) {
        int m = idxbuf[(size_t)p * KNN + j] & 2047;
        const int* mrow = idxbuf + (size_t)(b * NPT + m) * KNN;
        bool mut = false;
        for (int jj = 0; jj < KNN; jj++) mut = mut || (mrow[jj] == n);
        if (mut) {
            float prod = qv * kT[(size_t)(b * NPT + m) * 128 + t];
            prod += __shfl_xor(prod, 16);
            prod += __shfl_xor(prod, 8);
            prod += __shfl_xor(prod, 4);
            prod += __shfl_xor(prod, 2);
            prod += __shfl_xor(prod, 1);
            if ((t & 31) == 0) sbuf[cnt * 4 + h] = prod * 0.17677669529663687f;
            if (t == 0) mlist[cnt] = m;
            cnt++;
        }
    }
    __syncthreads();

    float mx = -3.4e38f;
    for (int j = 0; j < cnt; j++) mx = fmaxf(mx, sbuf[j * 4 + h]);
    float den = 0.f;
    for (int j = 0; j < cnt; j++) den += expf(sbuf[j * 4 + h] - mx);
    float inv = (cnt > 0) ? (1.0f / den) : 0.0f;
    float acc = 0.f;
    for (int j = 0; j < cnt; j++) {
        float pw = expf(sbuf[j * 4 + h] - mx) * inv;
        acc += pw * vT[(size_t)(b * NPT + mlist[j]) * 128 + t];
    }
    avT[(size_t)p * 128 + t] = acc;
}

// ---------------------------------------------------------------------------
// k4: avm = wm@av + bm; h = w1@[x; avm] + b1; BN partial sums.
// ---------------------------------------------------------------------------
__global__ __launch_bounds__(256) void k4_h(
    fp xbf, const float* avT, const float* wmT, fp bm,
    const float* w1T, fp b1, float* hbuf, float* stats) {
    __shared__ float avs[16][128];
    __shared__ float cvec[16][256];
    int t = threadIdx.x;
    int p0 = blockIdx.x * 16;
    int b = p0 >> 11, n0 = p0 & 2047;
    fp xb = xbf + (size_t)b * 128 * NPT;

    for (int r = 0; r < 8; r++) {
        int e = t + 256 * r;
        int p = e >> 7, c = e & 127;
        avs[p][c] = avT[(size_t)(p0 + p) * 128 + c];
    }
    {
        int c = t >> 1, half = t & 1;
        float4 f0 = *reinterpret_cast<const float4*>(xb + (size_t)c * NPT + n0 + half * 8);
        float4 f1 = *reinterpret_cast<const float4*>(xb + (size_t)c * NPT + n0 + half * 8 + 4);
        cvec[half * 8 + 0][c] = f0.x; cvec[half * 8 + 1][c] = f0.y;
        cvec[half * 8 + 2][c] = f0.z; cvec[half * 8 + 3][c] = f0.w;
        cvec[half * 8 + 4][c] = f1.x; cvec[half * 8 + 5][c] = f1.y;
        cvec[half * 8 + 6][c] = f1.z; cvec[half * 8 + 7][c] = f1.w;
    }
    __syncthreads();

    int o = t & 127, pg = t >> 7;
    float am[8];
    #pragma unroll
    for (int k = 0; k < 8; k++) am[k] = 0.f;
    for (int i = 0; i < 128; i++) {
        float w = wmT[i * 128 + o];
        #pragma unroll
        for (int k = 0; k < 8; k++) am[k] += w * avs[pg * 8 + k][i];
    }
    float bmv = bm[o];
    #pragma unroll
    for (int k = 0; k < 8; k++) cvec[pg * 8 + k][128 + o] = am[k] + bmv;
    __syncthreads();

    float hh[16];
    #pragma unroll
    for (int p = 0; p < 16; p++) hh[p] = 0.f;
    for (int i = 0; i < 256; i++) {
        float w = w1T[i * 256 + t];
        #pragma unroll
        for (int p = 0; p < 16; p++) hh[p] += w * cvec[p][i];
    }
    float b1v = b1[t];
    float s = 0.f, s2 = 0.f;
    for (int p = 0; p < 16; p++) {
        float v = hh[p] + b1v;
        hbuf[(size_t)(p0 + p) * 256 + t] = v;
        s += v; s2 += v * v;
    }
    atomicAdd(&stats[t], s);
    atomicAdd(&stats[256 + t], s2);
}

// ---------------------------------------------------------------------------
// k5: BN + ReLU + w2 conv + residual -> f32 out (B,C,N,1).
// ---------------------------------------------------------------------------
__global__ __launch_bounds__(256) void k5_out(
    const float* hbuf, const float* stats, fp gamma, fp beta,
    const float* w2T, fp b2, fp xbf, float* out) {
    __shared__ float hn[16][256];
    int t = threadIdx.x;
    int p0 = blockIdx.x * 16;
    int b = p0 >> 11, n0 = p0 & 2047;

    float mu  = stats[t] * (1.0f / 4096.0f);
    float var = stats[256 + t] * (1.0f / 4096.0f) - mu * mu;
    var = fmaxf(var, 0.0f);
    float a    = gamma[t] / sqrtf(var + 1e-5f);
    float cadd = beta[t] - mu * a;
    for (int r = 0; r < 16; r++) {
        float v = hbuf[(size_t)(p0 + r) * 256 + t] * a + cadd;
        hn[r][t] = fmaxf(v, 0.0f);
    }
    __syncthreads();

    int o = t & 127, pg = t >> 7;
    float acc[8];
    #pragma unroll
    for (int k = 0; k < 8; k++) acc[k] = 0.f;
    for (int i = 0; i < 256; i++) {
        float w = w2T[i * 128 + o];
        #pragma unroll
        for (int k = 0; k < 8; k++) acc[k] += w * hn[pg * 8 + k][i];
    }
    fp xb = xbf + (size_t)b * 128 * NPT;
    float4 x0 = *reinterpret_cast<const float4*>(xb + (size_t)o * NPT + n0 + pg * 8);
    float4 x1 = *reinterpret_cast<const float4*>(xb + (size_t)o * NPT + n0 + pg * 8 + 4);
    float xv[8] = {x0.x, x0.y, x0.z, x0.w, x1.x, x1.y, x1.z, x1.w};

    float b2v = b2[o];
    float4 o0, o1;
    o0.x = acc[0] + b2v + xv[0]; o0.y = acc[1] + b2v + xv[1];
    o0.z = acc[2] + b2v + xv[2]; o0.w = acc[3] + b2v + xv[3];
    o1.x = acc[4] + b2v + xv[4]; o1.y = acc[5] + b2v + xv[5];
    o1.z = acc[6] + b2v + xv[6]; o1.w = acc[7] + b2v + xv[7];
    size_t base = (size_t)b * 128 * NPT + (size_t)o * NPT + n0 + pg * 8;
    *reinterpret_cast<float4*>(out + base)     = o0;
    *reinterpret_cast<float4*>(out + base + 4) = o1;
}

// ---------------------------------------------------------------------------
// Workspace layout (28,264,448 B == round-6 WS_FULL, proven available):
//   0        qT 2MB [k1b->k3]    <- hbuf 4MB (k4->k5) aliases qT+kT
//   2097152  kT 2MB
//   4194304  vT 2MB
//   6291456  avT 2MB [k3->k4]
//   8388608  xx 16KB
//   8404992  idxb 320KB
//   8732672  stats 2KB
//   8734720  wmT 64KB | 8800256 w1T 256KB | 9062400 w2T 128KB
//   9193472  wqFhi/lo, wkFhi/lo, wvFhi/lo 6x32KB  (end 9390080)
//   9390080  xhiF 1MB | 10438656 xloF 1MB
//   11487232 key 16MB [k2a->k2b, reused per batch slab]
// ---------------------------------------------------------------------------
#define WS_FULL 28264448u

extern "C" void kernel_launch(void* const* d_in, const int* in_sizes, int n_in,
                              void* d_out, int out_size, void* d_ws, size_t ws_size,
                              hipStream_t stream) {
    fp desc1 = (fp)d_in[0];
    fp wq = (fp)d_in[1];  fp bq = (fp)d_in[2];
    fp wk = (fp)d_in[3];  fp bk = (fp)d_in[4];
    fp wv = (fp)d_in[5];  fp bv = (fp)d_in[6];
    fp wm = (fp)d_in[7];  fp bm = (fp)d_in[8];
    fp w1 = (fp)d_in[9];  fp b1 = (fp)d_in[10];
    fp gamma = (fp)d_in[11]; fp beta = (fp)d_in[12];
    fp w2 = (fp)d_in[13]; fp b2 = (fp)d_in[14];

    if (ws_size < (size_t)WS_FULL) return;  // all-zero out => ws too small

    char* ws = (char*)d_ws;
    float*  qT    = (float*) (ws + 0);
    float*  kT    = (float*) (ws + 2097152);
    float*  vT    = (float*) (ws + 4194304);
    float*  avT   = (float*) (ws + 6291456);
    float*  xx    = (float*) (ws + 8388608);
    int*    idxb  = (int*)   (ws + 8404992);
    float*  stats = (float*) (ws + 8732672);
    float*  wmT   = (float*) (ws + 8734720);
    float*  w1T   = (float*) (ws + 8800256);
    float*  w2T   = (float*) (ws + 9062400);
    ushort* wqFhi = (ushort*)(ws + 9193472);
    ushort* wqFlo = (ushort*)(ws + 9226240);
    ushort* wkFhi = (ushort*)(ws + 9259008);
    ushort* wkFlo = (ushort*)(ws + 9291776);
    ushort* wvFhi = (ushort*)(ws + 9324544);
    ushort* wvFlo = (ushort*)(ws + 9357312);
    ushort* xhiF  = (ushort*)(ws + 9390080);
    ushort* xloF  = (ushort*)(ws + 10438656);
    float*  key   = (float*) (ws + 11487232);
    float*  hbuf  = (float*) (ws + 0);      // aliases qT+kT (dead after k3)

    prep_w<<<642, 256, 0, stream>>>(wq, wk, wv, wm, w1, w2, wmT, w1T, w2T,
                                    wqFhi, wqFlo, wkFhi, wkFlo, wvFhi, wvFlo,
                                    stats);
    k1a_frag<<<256, 256, 0, stream>>>(desc1, xx, xhiF, xloF);
    k1b_qkv<<<384, 256, 0, stream>>>(xhiF, xloF, wqFhi, wqFlo, wkFhi, wkFlo,
                                     wvFhi, wvFlo, bq, bk, bv, qT, kT, vT);
    for (int s = 0; s < 2; s++) {
        k2a_gemm<<<1024, 256, 0, stream>>>(xhiF, xloF, xx, key, s * 2048);
        k2b_topk<<<512, 256, 0, stream>>>(key, idxb, s * 2048);
    }
    k3_attn<<<4096, 128, 0, stream>>>(qT, kT, vT, idxb, avT);
    k4_h<<<256, 256, 0, stream>>>(desc1, avT, wmT, bm, w1T, b1, hbuf, stats);
    k5_out<<<256, 256, 0, stream>>>(hbuf, stats, gamma, beta, w2T, b2, desc1,
                                    (float*)d_out);
}

// Round 8
// 246.991 us; speedup vs baseline: 1.2671x; 1.0992x over previous
//
#include <hip/hip_runtime.h>
#include <math.h>

#define NPT 2048
#define KNN 20

typedef const float* fp;
typedef __attribute__((ext_vector_type(4))) float f32x4;
typedef __attribute__((ext_vector_type(8))) short s16x8;

// round-to-nearest-even f32 -> bf16 bits (inputs are finite)
__device__ __forceinline__ ushort f2bf_rne(float v) {
    unsigned u = __float_as_uint(v);
    unsigned r = u + 0x7FFFu + ((u >> 16) & 1u);
    return (ushort)(r >> 16);
}
__device__ __forceinline__ float bfbits2f(ushort h) {
    return __uint_as_float(((unsigned)h) << 16);
}
__device__ __forceinline__ s16x8 ldfrag(const ushort* p) {
    union { uint4 u; s16x8 s; } cv;
    cv.u = *reinterpret_cast<const uint4*>(p);
    return cv.s;
}

// ---------------------------------------------------------------------------
// prep_w: (a) bf16 hi/lo MFMA B-fragments for wq/wk/wv; (b) f32 transposes
//         wmT/w1T/w2T; (c) zero BN stats.
// ---------------------------------------------------------------------------
__global__ void prep_w(fp wq, fp wk, fp wv, fp wm, fp w1, fp w2,
                       float* wmT, float* w1T, float* w2T,
                       ushort* wqFhi, ushort* wqFlo, ushort* wkFhi, ushort* wkFlo,
                       ushort* wvFhi, ushort* wvFlo, float* stats) {
    int t = blockIdx.x * 256 + threadIdx.x;
    if (t < 49152) {                        // q/k/v fragments (3 x 16384)
        int which = t >> 14, e = t & 16383;
        int lane = (e >> 3) & 63, j = e & 7, kk = (e >> 9) & 3, nt = e >> 11;
        int n = nt * 16 + (lane & 15);
        int k = kk * 32 + (lane >> 4) * 8 + j;
        fp src = which == 0 ? wq : which == 1 ? wk : wv;
        float v = src[n * 128 + k];
        ushort hi = f2bf_rne(v);
        float lo = v - bfbits2f(hi);
        (which == 0 ? wqFhi : which == 1 ? wkFhi : wvFhi)[e] = hi;
        (which == 0 ? wqFlo : which == 1 ? wkFlo : wvFlo)[e] = f2bf_rne(lo);
    } else if (t < 65536) {                 // wm 128x128 transpose
        int e = t - 49152; int o = e >> 7, i = e & 127;
        wmT[i * 128 + o] = wm[e];
    } else if (t < 131072) {                // w1 256x256 transpose
        int e = t - 65536; int o = e >> 8, i = e & 255;
        w1T[i * 256 + o] = w1[e];
    } else if (t < 163840) {                // w2 128x256 transpose
        int e = t - 131072; int o = e >> 8, i = e & 255;
        w2T[i * 128 + o] = w2[e];
    } else if (t < 164352) {                // BN stats zero
        stats[t - 163840] = 0.0f;
    }
}

// ---------------------------------------------------------------------------
// k1a: fragify x (bf16 hi/lo, MFMA A layout) + xx (sum of squares).
// ---------------------------------------------------------------------------
__global__ __launch_bounds__(256) void k1a_frag(
    fp xbf, float* xx, ushort* xhiF, ushort* xloF) {
    __shared__ float xs[16][129];
    __shared__ float xpart[16][17];
    int t = threadIdx.x;
    int p0 = blockIdx.x * 16;
    int b = p0 >> 11, n0 = p0 & 2047;
    fp xb = xbf + (size_t)b * 128 * NPT;

    {
        int c = t >> 1, half = t & 1;
        float4 f0 = *reinterpret_cast<const float4*>(xb + (size_t)c * NPT + n0 + half * 8);
        float4 f1 = *reinterpret_cast<const float4*>(xb + (size_t)c * NPT + n0 + half * 8 + 4);
        xs[half * 8 + 0][c] = f0.x; xs[half * 8 + 1][c] = f0.y;
        xs[half * 8 + 2][c] = f0.z; xs[half * 8 + 3][c] = f0.w;
        xs[half * 8 + 4][c] = f1.x; xs[half * 8 + 5][c] = f1.y;
        xs[half * 8 + 6][c] = f1.z; xs[half * 8 + 7][c] = f1.w;
    }
    __syncthreads();

    int p = t & 15, g = t >> 4, c0 = g * 8;
    float f[8];
    #pragma unroll
    for (int j = 0; j < 8; j++) f[j] = xs[p][c0 + j];
    float ps = 0.f;
    #pragma unroll
    for (int j = 0; j < 8; j++) ps += f[j] * f[j];
    xpart[p][g] = ps;

    union { ushort u[8]; uint4 q; } H, L;
    #pragma unroll
    for (int j = 0; j < 8; j++) {
        ushort hi = f2bf_rne(f[j]);
        H.u[j] = hi;
        L.u[j] = f2bf_rne(f[j] - bfbits2f(hi));
    }
    size_t off = ((size_t)blockIdx.x * 4 + (c0 >> 5)) * 512
               + (size_t)(((((c0 >> 3) & 3) * 16) + p) * 8);
    *reinterpret_cast<uint4*>(xhiF + off) = H.q;
    *reinterpret_cast<uint4*>(xloF + off) = L.q;

    __syncthreads();
    if (t < 16) {
        float s = 0.f;
        #pragma unroll
        for (int gg = 0; gg < 16; gg++) s += xpart[t][gg];
        xx[p0 + t] = s;
    }
}

// ---------------------------------------------------------------------------
// k1b: q/k/v GEMM via MFMA (hi/lo split).
// ---------------------------------------------------------------------------
__global__ __launch_bounds__(256) void k1b_qkv(
    const ushort* xhiF, const ushort* xloF,
    const ushort* wqFhi, const ushort* wqFlo,
    const ushort* wkFhi, const ushort* wkFlo,
    const ushort* wvFhi, const ushort* wvFlo,
    fp bq, fp bk, fp bv, float* qT, float* kT, float* vT) {
    int t = threadIdx.x, wvi = t >> 6, lane = t & 63;
    int gw = blockIdx.x * 4 + wvi;          // 0..1535
    int rt = gw / 6, rem = gw - rt * 6;
    int mat = rem >> 1, hf = rem & 1;
    const ushort* whi = mat == 0 ? wqFhi : mat == 1 ? wkFhi : wvFhi;
    const ushort* wlo = mat == 0 ? wqFlo : mat == 1 ? wkFlo : wvFlo;
    fp bias   = mat == 0 ? bq : mat == 1 ? bk : bv;
    float* out = mat == 0 ? qT : mat == 1 ? kT : vT;

    f32x4 acc[4];
    #pragma unroll
    for (int j = 0; j < 4; j++) acc[j] = (f32x4){0.f, 0.f, 0.f, 0.f};

    for (int kk = 0; kk < 4; kk++) {
        s16x8 ahi = ldfrag(xhiF + ((size_t)(rt * 4 + kk)) * 512 + lane * 8);
        s16x8 alo = ldfrag(xloF + ((size_t)(rt * 4 + kk)) * 512 + lane * 8);
        #pragma unroll
        for (int j = 0; j < 4; j++) {
            int nt = hf * 4 + j;
            s16x8 bhi = ldfrag(whi + ((size_t)(nt * 4 + kk)) * 512 + lane * 8);
            s16x8 blo = ldfrag(wlo + ((size_t)(nt * 4 + kk)) * 512 + lane * 8);
            acc[j] = __builtin_amdgcn_mfma_f32_16x16x32_bf16(ahi, bhi, acc[j], 0, 0, 0);
            acc[j] = __builtin_amdgcn_mfma_f32_16x16x32_bf16(alo, bhi, acc[j], 0, 0, 0);
            acc[j] = __builtin_amdgcn_mfma_f32_16x16x32_bf16(ahi, blo, acc[j], 0, 0, 0);
        }
    }
    int cl = lane & 15, quad = lane >> 4, p0 = rt * 16;
    #pragma unroll
    for (int j = 0; j < 4; j++) {
        int o = hf * 64 + j * 16 + cl;
        float bvv = bias[o];
        #pragma unroll
        for (int r = 0; r < 4; r++)
            out[(size_t)(p0 + quad * 4 + r) * 128 + o] = acc[j][r] + bvv;
    }
}

// ---------------------------------------------------------------------------
// k2a: key GEMM, one batch slab. Wave = 16 rows x 64 cols.
// ---------------------------------------------------------------------------
__global__ __launch_bounds__(256) void k2a_gemm(
    const ushort* xhiF, const ushort* xloF, const float* xx,
    float* key, int rowbase) {
    int t = threadIdx.x, wvi = t >> 6, lane = t & 63;
    int gw = blockIdx.x * 4 + wvi;          // 0..4095
    int rtl = gw >> 5;
    int cs  = gw & 31;
    int b   = rowbase >> 11;
    int rt  = (rowbase >> 4) + rtl;

    f32x4 acc[4];
    #pragma unroll
    for (int j = 0; j < 4; j++) acc[j] = (f32x4){0.f, 0.f, 0.f, 0.f};

    for (int kk = 0; kk < 4; kk++) {
        s16x8 ahi = ldfrag(xhiF + ((size_t)(rt * 4 + kk)) * 512 + lane * 8);
        s16x8 alo = ldfrag(xloF + ((size_t)(rt * 4 + kk)) * 512 + lane * 8);
        #pragma unroll
        for (int j = 0; j < 4; j++) {
            int ct = b * 128 + cs * 4 + j;
            s16x8 bhi = ldfrag(xhiF + ((size_t)(ct * 4 + kk)) * 512 + lane * 8);
            s16x8 blo = ldfrag(xloF + ((size_t)(ct * 4 + kk)) * 512 + lane * 8);
            acc[j] = __builtin_amdgcn_mfma_f32_16x16x32_bf16(ahi, bhi, acc[j], 0, 0, 0);
            acc[j] = __builtin_amdgcn_mfma_f32_16x16x32_bf16(alo, bhi, acc[j], 0, 0, 0);
            acc[j] = __builtin_amdgcn_mfma_f32_16x16x32_bf16(ahi, blo, acc[j], 0, 0, 0);
        }
    }
    int cl = lane & 15, quad = lane >> 4;
    #pragma unroll
    for (int j = 0; j < 4; j++) {
        int col = cs * 64 + j * 16 + cl;
        float xxv = xx[b * 2048 + col];
        #pragma unroll
        for (int r = 0; r < 4; r++)
            key[(size_t)(rtl * 16 + quad * 4 + r) * 2048 + col] = 2.0f * acc[j][r] - xxv;
    }
}

// ---------------------------------------------------------------------------
// k2b: per-row top-20 from key slab. Wave per row, register candidates.
// ---------------------------------------------------------------------------
#define MERGE(off) { float ov = __shfl_xor(bv, off); int oi = __shfl_xor(bi, off); \
                     if (ov > bv || (ov == bv && oi < bi)) { bv = ov; bi = oi; } }

__global__ __launch_bounds__(256) void k2b_topk(
    const float* key, int* idxbuf, int rowbase) {
    int t = threadIdx.x, wvi = t >> 6, lane = t & 63;
    int rowl = blockIdx.x * 4 + wvi;
    const float4* kr = reinterpret_cast<const float4*>(key + (size_t)rowl * 2048);
    float rv[32];
    #pragma unroll
    for (int j = 0; j < 8; j++) {
        float4 v = kr[j * 64 + lane];
        rv[j * 4 + 0] = v.x; rv[j * 4 + 1] = v.y;
        rv[j * 4 + 2] = v.z; rv[j * 4 + 3] = v.w;
    }
    unsigned removed = 0u;
    for (int iter = 0; iter < KNN; iter++) {
        float bv = -3.4e38f; int bi = 0;
        #pragma unroll
        for (int sl = 0; sl < 32; sl++) {
            bool live = ((removed >> sl) & 1u) == 0u;
            if (live && rv[sl] > bv) { bv = rv[sl]; bi = (sl >> 2) * 256 + lane * 4 + (sl & 3); }
        }
        MERGE(32) MERGE(16) MERGE(8) MERGE(4) MERGE(2) MERGE(1)
        bi &= 2047;
        if (lane == 0) idxbuf[(size_t)(rowbase + rowl) * KNN + iter] = bi;
        if (((bi >> 2) & 63) == lane) removed |= 1u << ((bi >> 8) * 4 + (bi & 3));
    }
}

// ---------------------------------------------------------------------------
// k2c: mutuality flags. One thread per (p, j): is n in idxbuf[neighbor]?
// ---------------------------------------------------------------------------
__global__ __launch_bounds__(256) void k2c_mutual(
    const int* idxbuf, unsigned char* mutflag) {
    int t = blockIdx.x * 256 + threadIdx.x;     // 0..81919
    int p = t / KNN, j = t - p * KNN;
    int b = p >> 11, n = p & 2047;
    int m = idxbuf[(size_t)p * KNN + j] & 2047;
    const int* mrow = idxbuf + (size_t)(b * NPT + m) * KNN;
    bool mut = false;
    #pragma unroll
    for (int jj = 0; jj < KNN; jj++) mut = mut || (mrow[jj] == n);
    mutflag[t] = mut ? 1 : 0;
}

// ---------------------------------------------------------------------------
// k3: sparse mutual-KNN attention. 256 threads = 2 points; mutual list built
//     by ballot (no serial scans); score/V loops are branch-free with
//     independent global loads (pipelinable).
// ---------------------------------------------------------------------------
__global__ __launch_bounds__(256) void k3_attn(
    fp qT, fp kT, fp vT, const int* idxbuf, const unsigned char* mutflag,
    float* avT) {
    __shared__ float sbuf[2][KNN * 4];
    __shared__ int   mlist[2][KNN];
    __shared__ int   cnt_s[2];
    int tt = threadIdx.x;
    int half = tt >> 7, t = tt & 127;
    int p = blockIdx.x * 2 + half;
    int b = p >> 11;
    int bbase = b * NPT;
    int h = t >> 5;

    if ((tt >> 6) == half * 2) {            // wave 0 of each half
        int lane = tt & 63;
        bool fl = false; int m = 0;
        if (lane < KNN) {
            m  = idxbuf[(size_t)p * KNN + lane] & 2047;
            fl = mutflag[(size_t)p * KNN + lane] != 0;
        }
        unsigned long long mask = __ballot(fl);
        int pos = __popcll(mask & ((1ull << lane) - 1ull));
        if (fl) mlist[half][pos] = m;
        if (lane == 0) cnt_s[half] = (int)__popcll(mask);
    }
    __syncthreads();

    int cnt = cnt_s[half];
    float qv = qT[(size_t)p * 128 + t];
    for (int jj = 0; jj < cnt; jj++) {
        int m = mlist[half][jj];
        float prod = qv * kT[(size_t)(bbase + m) * 128 + t];
        prod += __shfl_xor(prod, 16);
        prod += __shfl_xor(prod, 8);
        prod += __shfl_xor(prod, 4);
        prod += __shfl_xor(prod, 2);
        prod += __shfl_xor(prod, 1);
        if ((t & 31) == 0) sbuf[half][jj * 4 + h] = prod * 0.17677669529663687f;
    }
    __syncthreads();

    float mx = -3.4e38f;
    for (int j = 0; j < cnt; j++) mx = fmaxf(mx, sbuf[half][j * 4 + h]);
    float den = 0.f;
    for (int j = 0; j < cnt; j++) den += expf(sbuf[half][j * 4 + h] - mx);
    float inv = (cnt > 0) ? (1.0f / den) : 0.0f;
    float acc = 0.f;
    for (int j = 0; j < cnt; j++) {
        float pw = expf(sbuf[half][j * 4 + h] - mx) * inv;
        acc += pw * vT[(size_t)(bbase + mlist[half][j]) * 128 + t];
    }
    avT[(size_t)p * 128 + t] = acc;
}

// ---------------------------------------------------------------------------
// k4: avm = wm@av + bm; h = w1@[x; avm] + b1; BN partial sums.
//     8 points/block (512 blocks -> 2 blocks/CU).
// ---------------------------------------------------------------------------
__global__ __launch_bounds__(256) void k4_h(
    fp xbf, const float* avT, const float* wmT, fp bm,
    const float* w1T, fp b1, float* hbuf, float* stats) {
    __shared__ float avs[8][128];
    __shared__ float cvec[8][256];
    int t = threadIdx.x;
    int p0 = blockIdx.x * 8;
    int b = p0 >> 11, n0 = p0 & 2047;
    fp xb = xbf + (size_t)b * 128 * NPT;

    for (int r = 0; r < 4; r++) {
        int e = t + 256 * r;
        int p = e >> 7, c = e & 127;
        avs[p][c] = avT[(size_t)(p0 + p) * 128 + c];
    }
    {   // x part of cvec: thread (c = t&127, half = t>>7) loads 4 points
        int c = t & 127, half = t >> 7;
        float4 f = *reinterpret_cast<const float4*>(xb + (size_t)c * NPT + n0 + half * 4);
        cvec[half * 4 + 0][c] = f.x; cvec[half * 4 + 1][c] = f.y;
        cvec[half * 4 + 2][c] = f.z; cvec[half * 4 + 3][c] = f.w;
    }
    __syncthreads();

    int o = t & 127, pg = t >> 7;
    float am[4];
    #pragma unroll
    for (int k = 0; k < 4; k++) am[k] = 0.f;
    for (int i = 0; i < 128; i++) {
        float w = wmT[i * 128 + o];
        #pragma unroll
        for (int k = 0; k < 4; k++) am[k] += w * avs[pg * 4 + k][i];
    }
    float bmv = bm[o];
    #pragma unroll
    for (int k = 0; k < 4; k++) cvec[pg * 4 + k][128 + o] = am[k] + bmv;
    __syncthreads();

    float hh[8];
    #pragma unroll
    for (int p = 0; p < 8; p++) hh[p] = 0.f;
    for (int i = 0; i < 256; i++) {
        float w = w1T[i * 256 + t];
        #pragma unroll
        for (int p = 0; p < 8; p++) hh[p] += w * cvec[p][i];
    }
    float b1v = b1[t];
    float s = 0.f, s2 = 0.f;
    for (int p = 0; p < 8; p++) {
        float v = hh[p] + b1v;
        hbuf[(size_t)(p0 + p) * 256 + t] = v;
        s += v; s2 += v * v;
    }
    atomicAdd(&stats[t], s);
    atomicAdd(&stats[256 + t], s2);
}

// ---------------------------------------------------------------------------
// k5: BN + ReLU + w2 conv + residual -> f32 out. 8 points/block (512 blocks).
// ---------------------------------------------------------------------------
__global__ __launch_bounds__(256) void k5_out(
    const float* hbuf, const float* stats, fp gamma, fp beta,
    const float* w2T, fp b2, fp xbf, float* out) {
    __shared__ float hn[8][256];
    int t = threadIdx.x;
    int p0 = blockIdx.x * 8;
    int b = p0 >> 11, n0 = p0 & 2047;

    float mu  = stats[t] * (1.0f / 4096.0f);
    float var = stats[256 + t] * (1.0f / 4096.0f) - mu * mu;
    var = fmaxf(var, 0.0f);
    float a    = gamma[t] / sqrtf(var + 1e-5f);
    float cadd = beta[t] - mu * a;
    for (int r = 0; r < 8; r++) {
        float v = hbuf[(size_t)(p0 + r) * 256 + t] * a + cadd;
        hn[r][t] = fmaxf(v, 0.0f);
    }
    __syncthreads();

    int o = t & 127, pg = t >> 7;
    float acc[4];
    #pragma unroll
    for (int k = 0; k < 4; k++) acc[k] = 0.f;
    for (int i = 0; i < 256; i++) {
        float w = w2T[i * 128 + o];
        #pragma unroll
        for (int k = 0; k < 4; k++) acc[k] += w * hn[pg * 4 + k][i];
    }
    fp xb = xbf + (size_t)b * 128 * NPT;
    float4 x0 = *reinterpret_cast<const float4*>(xb + (size_t)o * NPT + n0 + pg * 4);

    float b2v = b2[o];
    float4 o0;
    o0.x = acc[0] + b2v + x0.x; o0.y = acc[1] + b2v + x0.y;
    o0.z = acc[2] + b2v + x0.z; o0.w = acc[3] + b2v + x0.w;
    size_t base = (size_t)b * 128 * NPT + (size_t)o * NPT + n0 + pg * 4;
    *reinterpret_cast<float4*>(out + base) = o0;
}

// ---------------------------------------------------------------------------
// Workspace layout (28,346,368 B; observed ws ≈ 268 MB — plenty):
//   0        qT 2MB [k1b->k3]    <- hbuf 4MB (k4->k5) aliases qT+kT
//   2097152  kT 2MB
//   4194304  vT 2MB
//   6291456  avT 2MB [k3->k4]
//   8388608  xx 16KB
//   8404992  idxb 320KB
//   8732672  stats 2KB
//   8734720  wmT 64KB | 8800256 w1T 256KB | 9062400 w2T 128KB
//   9193472  wqFhi/lo, wkFhi/lo, wvFhi/lo 6x32KB
//   9390080  xhiF 1MB | 10438656 xloF 1MB
//   11487232 key 16MB [k2a->k2b, reused per batch slab]
//   28264448 mutflag 80KB [k2c->k3]
// ---------------------------------------------------------------------------
#define WS_FULL 28346368u

extern "C" void kernel_launch(void* const* d_in, const int* in_sizes, int n_in,
                              void* d_out, int out_size, void* d_ws, size_t ws_size,
                              hipStream_t stream) {
    fp desc1 = (fp)d_in[0];
    fp wq = (fp)d_in[1];  fp bq = (fp)d_in[2];
    fp wk = (fp)d_in[3];  fp bk = (fp)d_in[4];
    fp wv = (fp)d_in[5];  fp bv = (fp)d_in[6];
    fp wm = (fp)d_in[7];  fp bm = (fp)d_in[8];
    fp w1 = (fp)d_in[9];  fp b1 = (fp)d_in[10];
    fp gamma = (fp)d_in[11]; fp beta = (fp)d_in[12];
    fp w2 = (fp)d_in[13]; fp b2 = (fp)d_in[14];

    if (ws_size < (size_t)WS_FULL) return;  // all-zero out => ws too small

    char* ws = (char*)d_ws;
    float*  qT    = (float*) (ws + 0);
    float*  kT    = (float*) (ws + 2097152);
    float*  vT    = (float*) (ws + 4194304);
    float*  avT   = (float*) (ws + 6291456);
    float*  xx    = (float*) (ws + 8388608);
    int*    idxb  = (int*)   (ws + 8404992);
    float*  stats = (float*) (ws + 8732672);
    float*  wmT   = (float*) (ws + 8734720);
    float*  w1T   = (float*) (ws + 8800256);
    float*  w2T   = (float*) (ws + 9062400);
    ushort* wqFhi = (ushort*)(ws + 9193472);
    ushort* wqFlo = (ushort*)(ws + 9226240);
    ushort* wkFhi = (ushort*)(ws + 9259008);
    ushort* wkFlo = (ushort*)(ws + 9291776);
    ushort* wvFhi = (ushort*)(ws + 9324544);
    ushort* wvFlo = (ushort*)(ws + 9357312);
    ushort* xhiF  = (ushort*)(ws + 9390080);
    ushort* xloF  = (ushort*)(ws + 10438656);
    float*  key   = (float*) (ws + 11487232);
    unsigned char* mutflag = (unsigned char*)(ws + 28264448);
    float*  hbuf  = (float*) (ws + 0);      // aliases qT+kT (dead after k3)

    prep_w<<<642, 256, 0, stream>>>(wq, wk, wv, wm, w1, w2, wmT, w1T, w2T,
                                    wqFhi, wqFlo, wkFhi, wkFlo, wvFhi, wvFlo,
                                    stats);
    k1a_frag<<<256, 256, 0, stream>>>(desc1, xx, xhiF, xloF);
    k1b_qkv<<<384, 256, 0, stream>>>(xhiF, xloF, wqFhi, wqFlo, wkFhi, wkFlo,
                                     wvFhi, wvFlo, bq, bk, bv, qT, kT, vT);
    for (int s = 0; s < 2; s++) {
        k2a_gemm<<<1024, 256, 0, stream>>>(xhiF, xloF, xx, key, s * 2048);
        k2b_topk<<<512, 256, 0, stream>>>(key, idxb, s * 2048);
    }
    k2c_mutual<<<320, 256, 0, stream>>>(idxb, mutflag);
    k3_attn<<<2048, 256, 0, stream>>>(qT, kT, vT, idxb, mutflag, avT);
    k4_h<<<512, 256, 0, stream>>>(desc1, avT, wmT, bm, w1T, b1, hbuf, stats);
    k5_out<<<512, 256, 0, stream>>>(hbuf, stats, gamma, beta, w2T, b2, desc1,
                                    (float*)d_out);
}

// Round 9
// 234.698 us; speedup vs baseline: 1.3335x; 1.0524x over previous
//
#include <hip/hip_runtime.h>
#include <math.h>

#define NPT 2048
#define KNN 20

typedef const float* fp;
typedef __attribute__((ext_vector_type(4))) float f32x4;
typedef __attribute__((ext_vector_type(8))) short s16x8;

// round-to-nearest-even f32 -> bf16 bits (inputs are finite)
__device__ __forceinline__ ushort f2bf_rne(float v) {
    unsigned u = __float_as_uint(v);
    unsigned r = u + 0x7FFFu + ((u >> 16) & 1u);
    return (ushort)(r >> 16);
}
__device__ __forceinline__ float bfbits2f(ushort h) {
    return __uint_as_float(((unsigned)h) << 16);
}
__device__ __forceinline__ s16x8 ldfrag(const ushort* p) {
    union { uint4 u; s16x8 s; } cv;
    cv.u = *reinterpret_cast<const uint4*>(p);
    return cv.s;
}

// ---------------------------------------------------------------------------
// prep1: W = w1a @ wm  (256x128, w1a = w1[:,128:256]); b1p = b1 + w1a @ bm.
// ---------------------------------------------------------------------------
__global__ void prep1(fp w1, fp wm, fp bm, fp b1, float* Wbuf, float* b1p) {
    int t = blockIdx.x * 256 + threadIdx.x;
    if (t < 32768) {
        int o = t >> 7, c = t & 127;
        float s = 0.f;
        for (int i = 0; i < 128; i++)
            s += w1[o * 256 + 128 + i] * wm[i * 128 + c];
        Wbuf[t] = s;
    } else if (t < 33024) {
        int o = t - 32768;
        float s = b1[o];
        for (int i = 0; i < 128; i++)
            s += w1[o * 256 + 128 + i] * bm[i];
        b1p[o] = s;
    }
}

// ---------------------------------------------------------------------------
// prep2: bf16 hi/lo MFMA B-fragments for wq/wk/wv (K=128), wc=[w1x|W] (K=256),
//        w2 (K=256); zero BN stats. Frag addressing (NKK = K/32):
//        off = (nt*NKK + kk)*512 + lane*8 + j, lane = (n&15)|(((k>>3)&3)<<4),
//        j = k&7, kk = k>>5.
// ---------------------------------------------------------------------------
__global__ void prep2(fp wq, fp wk, fp wv, fp w1, const float* Wbuf, fp w2,
                      ushort* wqFhi, ushort* wqFlo, ushort* wkFhi, ushort* wkFlo,
                      ushort* wvFhi, ushort* wvFlo,
                      ushort* wcFhi, ushort* wcFlo, ushort* w2Fhi, ushort* w2Flo,
                      float* stats) {
    int t = blockIdx.x * 256 + threadIdx.x;
    if (t < 49152) {                        // q/k/v frags (3 x 16384, K=128)
        int which = t >> 14, e = t & 16383;
        int lane = (e >> 3) & 63, j = e & 7, kk = (e >> 9) & 3, nt = e >> 11;
        int n = nt * 16 + (lane & 15);
        int k = kk * 32 + (lane >> 4) * 8 + j;
        fp src = which == 0 ? wq : which == 1 ? wk : wv;
        float v = src[n * 128 + k];
        ushort hi = f2bf_rne(v);
        (which == 0 ? wqFhi : which == 1 ? wkFhi : wvFhi)[e] = hi;
        (which == 0 ? wqFlo : which == 1 ? wkFlo : wvFlo)[e] = f2bf_rne(v - bfbits2f(hi));
    } else if (t < 114688) {                // wc frags (65536, N=256, K=256)
        int e = t - 49152;
        int j = e & 7, lane = (e >> 3) & 63, kk = (e >> 9) & 7, nt = e >> 12;
        int n = nt * 16 + (lane & 15);
        int k = kk * 32 + (lane >> 4) * 8 + j;
        float v = (k < 128) ? w1[n * 256 + k] : Wbuf[n * 128 + (k - 128)];
        ushort hi = f2bf_rne(v);
        wcFhi[e] = hi;
        wcFlo[e] = f2bf_rne(v - bfbits2f(hi));
    } else if (t < 147456) {                // w2 frags (32768, N=128, K=256)
        int e = t - 114688;
        int j = e & 7, lane = (e >> 3) & 63, kk = (e >> 9) & 7, nt = e >> 12;
        int n = nt * 16 + (lane & 15);
        int k = kk * 32 + (lane >> 4) * 8 + j;
        float v = w2[n * 256 + k];
        ushort hi = f2bf_rne(v);
        w2Fhi[e] = hi;
        w2Flo[e] = f2bf_rne(v - bfbits2f(hi));
    } else if (t < 147968) {                // BN stats zero
        stats[t - 147456] = 0.0f;
    }
}

// ---------------------------------------------------------------------------
// k1a: fragify x (bf16 hi/lo, MFMA A layout) + xx (sum of squares).
// ---------------------------------------------------------------------------
__global__ __launch_bounds__(256) void k1a_frag(
    fp xbf, float* xx, ushort* xhiF, ushort* xloF) {
    __shared__ float xs[16][129];
    __shared__ float xpart[16][17];
    int t = threadIdx.x;
    int p0 = blockIdx.x * 16;
    int b = p0 >> 11, n0 = p0 & 2047;
    fp xb = xbf + (size_t)b * 128 * NPT;

    {
        int c = t >> 1, half = t & 1;
        float4 f0 = *reinterpret_cast<const float4*>(xb + (size_t)c * NPT + n0 + half * 8);
        float4 f1 = *reinterpret_cast<const float4*>(xb + (size_t)c * NPT + n0 + half * 8 + 4);
        xs[half * 8 + 0][c] = f0.x; xs[half * 8 + 1][c] = f0.y;
        xs[half * 8 + 2][c] = f0.z; xs[half * 8 + 3][c] = f0.w;
        xs[half * 8 + 4][c] = f1.x; xs[half * 8 + 5][c] = f1.y;
        xs[half * 8 + 6][c] = f1.z; xs[half * 8 + 7][c] = f1.w;
    }
    __syncthreads();

    int p = t & 15, g = t >> 4, c0 = g * 8;
    float f[8];
    #pragma unroll
    for (int j = 0; j < 8; j++) f[j] = xs[p][c0 + j];
    float ps = 0.f;
    #pragma unroll
    for (int j = 0; j < 8; j++) ps += f[j] * f[j];
    xpart[p][g] = ps;

    union { ushort u[8]; uint4 q; } H, L;
    #pragma unroll
    for (int j = 0; j < 8; j++) {
        ushort hi = f2bf_rne(f[j]);
        H.u[j] = hi;
        L.u[j] = f2bf_rne(f[j] - bfbits2f(hi));
    }
    size_t off = ((size_t)blockIdx.x * 4 + (c0 >> 5)) * 512
               + (size_t)(((((c0 >> 3) & 3) * 16) + p) * 8);
    *reinterpret_cast<uint4*>(xhiF + off) = H.q;
    *reinterpret_cast<uint4*>(xloF + off) = L.q;

    __syncthreads();
    if (t < 16) {
        float s = 0.f;
        #pragma unroll
        for (int gg = 0; gg < 16; gg++) s += xpart[t][gg];
        xx[p0 + t] = s;
    }
}

// ---------------------------------------------------------------------------
// fragify128: f32 point-major [p][128] -> bf16 hi/lo MFMA A-frags.
// ---------------------------------------------------------------------------
__global__ __launch_bounds__(256) void fragify128(
    const float* src, ushort* hiF, ushort* loF) {
    int t = threadIdx.x;
    int p0 = blockIdx.x * 16;
    int g = t & 15, p = t >> 4, c0 = g * 8;   // lanes consecutive g: coalesced
    const float* row = src + (size_t)(p0 + p) * 128 + c0;
    float4 f0 = *reinterpret_cast<const float4*>(row);
    float4 f1 = *reinterpret_cast<const float4*>(row + 4);
    float f[8] = {f0.x, f0.y, f0.z, f0.w, f1.x, f1.y, f1.z, f1.w};
    union { ushort u[8]; uint4 q; } H, L;
    #pragma unroll
    for (int j = 0; j < 8; j++) {
        ushort hi = f2bf_rne(f[j]);
        H.u[j] = hi;
        L.u[j] = f2bf_rne(f[j] - bfbits2f(hi));
    }
    size_t off = ((size_t)blockIdx.x * 4 + (c0 >> 5)) * 512
               + (size_t)(((((c0 >> 3) & 3) * 16) + p) * 8);
    *reinterpret_cast<uint4*>(hiF + off) = H.q;
    *reinterpret_cast<uint4*>(loF + off) = L.q;
}

// ---------------------------------------------------------------------------
// k1b: q/k/v GEMM via MFMA (hi/lo split).
// ---------------------------------------------------------------------------
__global__ __launch_bounds__(256) void k1b_qkv(
    const ushort* xhiF, const ushort* xloF,
    const ushort* wqFhi, const ushort* wqFlo,
    const ushort* wkFhi, const ushort* wkFlo,
    const ushort* wvFhi, const ushort* wvFlo,
    fp bq, fp bk, fp bv, float* qT, float* kT, float* vT) {
    int t = threadIdx.x, wvi = t >> 6, lane = t & 63;
    int gw = blockIdx.x * 4 + wvi;          // 0..1535
    int rt = gw / 6, rem = gw - rt * 6;
    int mat = rem >> 1, hf = rem & 1;
    const ushort* whi = mat == 0 ? wqFhi : mat == 1 ? wkFhi : wvFhi;
    const ushort* wlo = mat == 0 ? wqFlo : mat == 1 ? wkFlo : wvFlo;
    fp bias   = mat == 0 ? bq : mat == 1 ? bk : bv;
    float* out = mat == 0 ? qT : mat == 1 ? kT : vT;

    f32x4 acc[4];
    #pragma unroll
    for (int j = 0; j < 4; j++) acc[j] = (f32x4){0.f, 0.f, 0.f, 0.f};

    for (int kk = 0; kk < 4; kk++) {
        s16x8 ahi = ldfrag(xhiF + ((size_t)(rt * 4 + kk)) * 512 + lane * 8);
        s16x8 alo = ldfrag(xloF + ((size_t)(rt * 4 + kk)) * 512 + lane * 8);
        #pragma unroll
        for (int j = 0; j < 4; j++) {
            int nt = hf * 4 + j;
            s16x8 bhi = ldfrag(whi + ((size_t)(nt * 4 + kk)) * 512 + lane * 8);
            s16x8 blo = ldfrag(wlo + ((size_t)(nt * 4 + kk)) * 512 + lane * 8);
            acc[j] = __builtin_amdgcn_mfma_f32_16x16x32_bf16(ahi, bhi, acc[j], 0, 0, 0);
            acc[j] = __builtin_amdgcn_mfma_f32_16x16x32_bf16(alo, bhi, acc[j], 0, 0, 0);
            acc[j] = __builtin_amdgcn_mfma_f32_16x16x32_bf16(ahi, blo, acc[j], 0, 0, 0);
        }
    }
    int cl = lane & 15, quad = lane >> 4, p0 = rt * 16;
    #pragma unroll
    for (int j = 0; j < 4; j++) {
        int o = hf * 64 + j * 16 + cl;
        float bvv = bias[o];
        #pragma unroll
        for (int r = 0; r < 4; r++)
            out[(size_t)(p0 + quad * 4 + r) * 128 + o] = acc[j][r] + bvv;
    }
}

// ---------------------------------------------------------------------------
// k2a: key GEMM, one batch slab. Wave = 16 rows x 64 cols.
// ---------------------------------------------------------------------------
__global__ __launch_bounds__(256) void k2a_gemm(
    const ushort* xhiF, const ushort* xloF, const float* xx,
    float* key, int rowbase) {
    int t = threadIdx.x, wvi = t >> 6, lane = t & 63;
    int gw = blockIdx.x * 4 + wvi;          // 0..4095
    int rtl = gw >> 5;
    int cs  = gw & 31;
    int b   = rowbase >> 11;
    int rt  = (rowbase >> 4) + rtl;

    f32x4 acc[4];
    #pragma unroll
    for (int j = 0; j < 4; j++) acc[j] = (f32x4){0.f, 0.f, 0.f, 0.f};

    for (int kk = 0; kk < 4; kk++) {
        s16x8 ahi = ldfrag(xhiF + ((size_t)(rt * 4 + kk)) * 512 + lane * 8);
        s16x8 alo = ldfrag(xloF + ((size_t)(rt * 4 + kk)) * 512 + lane * 8);
        #pragma unroll
        for (int j = 0; j < 4; j++) {
            int ct = b * 128 + cs * 4 + j;
            s16x8 bhi = ldfrag(xhiF + ((size_t)(ct * 4 + kk)) * 512 + lane * 8);
            s16x8 blo = ldfrag(xloF + ((size_t)(ct * 4 + kk)) * 512 + lane * 8);
            acc[j] = __builtin_amdgcn_mfma_f32_16x16x32_bf16(ahi, bhi, acc[j], 0, 0, 0);
            acc[j] = __builtin_amdgcn_mfma_f32_16x16x32_bf16(alo, bhi, acc[j], 0, 0, 0);
            acc[j] = __builtin_amdgcn_mfma_f32_16x16x32_bf16(ahi, blo, acc[j], 0, 0, 0);
        }
    }
    int cl = lane & 15, quad = lane >> 4;
    #pragma unroll
    for (int j = 0; j < 4; j++) {
        int col = cs * 64 + j * 16 + cl;
        float xxv = xx[b * 2048 + col];
        #pragma unroll
        for (int r = 0; r < 4; r++)
            key[(size_t)(rtl * 16 + quad * 4 + r) * 2048 + col] = 2.0f * acc[j][r] - xxv;
    }
}

// ---------------------------------------------------------------------------
// k2b: per-row top-20 from key slab. Wave per row, register candidates.
// ---------------------------------------------------------------------------
#define MERGE(off) { float ov = __shfl_xor(bv, off); int oi = __shfl_xor(bi, off); \
                     if (ov > bv || (ov == bv && oi < bi)) { bv = ov; bi = oi; } }

__global__ __launch_bounds__(256) void k2b_topk(
    const float* key, int* idxbuf, int rowbase) {
    int t = threadIdx.x, wvi = t >> 6, lane = t & 63;
    int rowl = blockIdx.x * 4 + wvi;
    const float4* kr = reinterpret_cast<const float4*>(key + (size_t)rowl * 2048);
    float rv[32];
    #pragma unroll
    for (int j = 0; j < 8; j++) {
        float4 v = kr[j * 64 + lane];
        rv[j * 4 + 0] = v.x; rv[j * 4 + 1] = v.y;
        rv[j * 4 + 2] = v.z; rv[j * 4 + 3] = v.w;
    }
    unsigned removed = 0u;
    for (int iter = 0; iter < KNN; iter++) {
        float bv = -3.4e38f; int bi = 0;
        #pragma unroll
        for (int sl = 0; sl < 32; sl++) {
            bool live = ((removed >> sl) & 1u) == 0u;
            if (live && rv[sl] > bv) { bv = rv[sl]; bi = (sl >> 2) * 256 + lane * 4 + (sl & 3); }
        }
        MERGE(32) MERGE(16) MERGE(8) MERGE(4) MERGE(2) MERGE(1)
        bi &= 2047;
        if (lane == 0) idxbuf[(size_t)(rowbase + rowl) * KNN + iter] = bi;
        if (((bi >> 2) & 63) == lane) removed |= 1u << ((bi >> 8) * 4 + (bi & 3));
    }
}

// ---------------------------------------------------------------------------
// k2c: mutuality flags. One thread per (p, j).
// ---------------------------------------------------------------------------
__global__ __launch_bounds__(256) void k2c_mutual(
    const int* idxbuf, unsigned char* mutflag) {
    int t = blockIdx.x * 256 + threadIdx.x;
    int p = t / KNN, j = t - p * KNN;
    int b = p >> 11, n = p & 2047;
    int m = idxbuf[(size_t)p * KNN + j] & 2047;
    const int* mrow = idxbuf + (size_t)(b * NPT + m) * KNN;
    bool mut = false;
    #pragma unroll
    for (int jj = 0; jj < KNN; jj++) mut = mut || (mrow[jj] == n);
    mutflag[t] = mut ? 1 : 0;
}

// ---------------------------------------------------------------------------
// k3: sparse mutual-KNN attention. 256 threads = 2 points.
// ---------------------------------------------------------------------------
__global__ __launch_bounds__(256) void k3_attn(
    fp qT, fp kT, fp vT, const int* idxbuf, const unsigned char* mutflag,
    float* avT) {
    __shared__ float sbuf[2][KNN * 4];
    __shared__ int   mlist[2][KNN];
    __shared__ int   cnt_s[2];
    int tt = threadIdx.x;
    int half = tt >> 7, t = tt & 127;
    int p = blockIdx.x * 2 + half;
    int b = p >> 11;
    int bbase = b * NPT;
    int h = t >> 5;

    if ((tt >> 6) == half * 2) {
        int lane = tt & 63;
        bool fl = false; int m = 0;
        if (lane < KNN) {
            m  = idxbuf[(size_t)p * KNN + lane] & 2047;
            fl = mutflag[(size_t)p * KNN + lane] != 0;
        }
        unsigned long long mask = __ballot(fl);
        int pos = __popcll(mask & ((1ull << lane) - 1ull));
        if (fl) mlist[half][pos] = m;
        if (lane == 0) cnt_s[half] = (int)__popcll(mask);
    }
    __syncthreads();

    int cnt = cnt_s[half];
    float qv = qT[(size_t)p * 128 + t];
    for (int jj = 0; jj < cnt; jj++) {
        int m = mlist[half][jj];
        float prod = qv * kT[(size_t)(bbase + m) * 128 + t];
        prod += __shfl_xor(prod, 16);
        prod += __shfl_xor(prod, 8);
        prod += __shfl_xor(prod, 4);
        prod += __shfl_xor(prod, 2);
        prod += __shfl_xor(prod, 1);
        if ((t & 31) == 0) sbuf[half][jj * 4 + h] = prod * 0.17677669529663687f;
    }
    __syncthreads();

    float mx = -3.4e38f;
    for (int j = 0; j < cnt; j++) mx = fmaxf(mx, sbuf[half][j * 4 + h]);
    float den = 0.f;
    for (int j = 0; j < cnt; j++) den += expf(sbuf[half][j * 4 + h] - mx);
    float inv = (cnt > 0) ? (1.0f / den) : 0.0f;
    float acc = 0.f;
    for (int j = 0; j < cnt; j++) {
        float pw = expf(sbuf[half][j * 4 + h] - mx) * inv;
        acc += pw * vT[(size_t)(bbase + mlist[half][j]) * 128 + t];
    }
    avT[(size_t)p * 128 + t] = acc;
}

// ---------------------------------------------------------------------------
// k4b: h = w1x@x + W@av + b1p via MFMA (K=256: x frags kk 0..3, av frags
//      kk 4..7; B = wc frags). Epilogue: hbuf write + wave-reduced BN stats.
//      Block = row-tile rt (16 points); 4 waves = 4 col-strips of 64.
// ---------------------------------------------------------------------------
__global__ __launch_bounds__(256) void k4b_h(
    const ushort* xhiF, const ushort* xloF,
    const ushort* avFhi, const ushort* avFlo,
    const ushort* wcFhi, const ushort* wcFlo,
    const float* b1p, float* hbuf, float* stats) {
    int t = threadIdx.x, cs = t >> 6, lane = t & 63;
    int rt = blockIdx.x;                    // 0..255

    f32x4 acc[4];
    #pragma unroll
    for (int j = 0; j < 4; j++) acc[j] = (f32x4){0.f, 0.f, 0.f, 0.f};

    for (int kk = 0; kk < 4; kk++) {
        s16x8 ahi = ldfrag(xhiF + ((size_t)(rt * 4 + kk)) * 512 + lane * 8);
        s16x8 alo = ldfrag(xloF + ((size_t)(rt * 4 + kk)) * 512 + lane * 8);
        #pragma unroll
        for (int j = 0; j < 4; j++) {
            int nt = cs * 4 + j;
            s16x8 bhi = ldfrag(wcFhi + ((size_t)(nt * 8 + kk)) * 512 + lane * 8);
            s16x8 blo = ldfrag(wcFlo + ((size_t)(nt * 8 + kk)) * 512 + lane * 8);
            acc[j] = __builtin_amdgcn_mfma_f32_16x16x32_bf16(ahi, bhi, acc[j], 0, 0, 0);
            acc[j] = __builtin_amdgcn_mfma_f32_16x16x32_bf16(alo, bhi, acc[j], 0, 0, 0);
            acc[j] = __builtin_amdgcn_mfma_f32_16x16x32_bf16(ahi, blo, acc[j], 0, 0, 0);
        }
    }
    for (int kk = 4; kk < 8; kk++) {
        s16x8 ahi = ldfrag(avFhi + ((size_t)(rt * 4 + kk - 4)) * 512 + lane * 8);
        s16x8 alo = ldfrag(avFlo + ((size_t)(rt * 4 + kk - 4)) * 512 + lane * 8);
        #pragma unroll
        for (int j = 0; j < 4; j++) {
            int nt = cs * 4 + j;
            s16x8 bhi = ldfrag(wcFhi + ((size_t)(nt * 8 + kk)) * 512 + lane * 8);
            s16x8 blo = ldfrag(wcFlo + ((size_t)(nt * 8 + kk)) * 512 + lane * 8);
            acc[j] = __builtin_amdgcn_mfma_f32_16x16x32_bf16(ahi, bhi, acc[j], 0, 0, 0);
            acc[j] = __builtin_amdgcn_mfma_f32_16x16x32_bf16(alo, bhi, acc[j], 0, 0, 0);
            acc[j] = __builtin_amdgcn_mfma_f32_16x16x32_bf16(ahi, blo, acc[j], 0, 0, 0);
        }
    }

    int cl = lane & 15, quad = lane >> 4, p0 = rt * 16;
    #pragma unroll
    for (int j = 0; j < 4; j++) {
        int o = cs * 64 + j * 16 + cl;
        float bb = b1p[o];
        float s = 0.f, s2 = 0.f;
        #pragma unroll
        for (int r = 0; r < 4; r++) {
            float v = acc[j][r] + bb;
            hbuf[(size_t)(p0 + quad * 4 + r) * 256 + o] = v;
            s += v; s2 += v * v;
        }
        s  += __shfl_xor(s, 16);  s  += __shfl_xor(s, 32);
        s2 += __shfl_xor(s2, 16); s2 += __shfl_xor(s2, 32);
        if (quad == 0) {
            atomicAdd(&stats[o], s);
            atomicAdd(&stats[256 + o], s2);
        }
    }
}

// ---------------------------------------------------------------------------
// k5f: BN + ReLU + bf16 hi/lo fragify of h (K=256 A-frags for k5b).
// ---------------------------------------------------------------------------
__global__ __launch_bounds__(256) void k5f_frag(
    const float* hbuf, const float* stats, fp gamma, fp beta,
    ushort* hFhi, ushort* hFlo) {
    int t = threadIdx.x;
    int p0 = blockIdx.x * 16;
    #pragma unroll
    for (int it = 0; it < 2; it++) {
        int item = t + 256 * it;            // 0..511
        int g = item & 31, p = item >> 5, c0 = g * 8;
        const float* row = hbuf + (size_t)(p0 + p) * 256 + c0;
        float4 f0 = *reinterpret_cast<const float4*>(row);
        float4 f1 = *reinterpret_cast<const float4*>(row + 4);
        float f[8] = {f0.x, f0.y, f0.z, f0.w, f1.x, f1.y, f1.z, f1.w};
        union { ushort u[8]; uint4 q; } H, L;
        #pragma unroll
        for (int j = 0; j < 8; j++) {
            int c = c0 + j;
            float mu  = stats[c] * (1.0f / 4096.0f);
            float var = fmaxf(stats[256 + c] * (1.0f / 4096.0f) - mu * mu, 0.0f);
            float a    = gamma[c] / sqrtf(var + 1e-5f);
            float cadd = beta[c] - mu * a;
            float v = fmaxf(f[j] * a + cadd, 0.0f);
            ushort hi = f2bf_rne(v);
            H.u[j] = hi;
            L.u[j] = f2bf_rne(v - bfbits2f(hi));
        }
        size_t off = ((size_t)blockIdx.x * 8 + (c0 >> 5)) * 512
                   + (size_t)(((((c0 >> 3) & 3) * 16) + p) * 8);
        *reinterpret_cast<uint4*>(hFhi + off) = H.q;
        *reinterpret_cast<uint4*>(hFlo + off) = L.q;
    }
}

// ---------------------------------------------------------------------------
// k5b: out = w2@hn + b2 + x via MFMA (K=256). Epilogue: float4 stores in
//      (B,C,N) with residual.
// ---------------------------------------------------------------------------
__global__ __launch_bounds__(256) void k5b_out(
    const ushort* hFhi, const ushort* hFlo,
    const ushort* w2Fhi, const ushort* w2Flo,
    fp b2, fp xbf, float* out) {
    int t = threadIdx.x, wvi = t >> 6, lane = t & 63;
    int gw = blockIdx.x * 4 + wvi;          // 0..511
    int rt = gw >> 1, cs = gw & 1;

    f32x4 acc[4];
    #pragma unroll
    for (int j = 0; j < 4; j++) acc[j] = (f32x4){0.f, 0.f, 0.f, 0.f};

    for (int kk = 0; kk < 8; kk++) {
        s16x8 ahi = ldfrag(hFhi + ((size_t)(rt * 8 + kk)) * 512 + lane * 8);
        s16x8 alo = ldfrag(hFlo + ((size_t)(rt * 8 + kk)) * 512 + lane * 8);
        #pragma unroll
        for (int j = 0; j < 4; j++) {
            int nt = cs * 4 + j;
            s16x8 bhi = ldfrag(w2Fhi + ((size_t)(nt * 8 + kk)) * 512 + lane * 8);
            s16x8 blo = ldfrag(w2Flo + ((size_t)(nt * 8 + kk)) * 512 + lane * 8);
            acc[j] = __builtin_amdgcn_mfma_f32_16x16x32_bf16(ahi, bhi, acc[j], 0, 0, 0);
            acc[j] = __builtin_amdgcn_mfma_f32_16x16x32_bf16(alo, bhi, acc[j], 0, 0, 0);
            acc[j] = __builtin_amdgcn_mfma_f32_16x16x32_bf16(ahi, blo, acc[j], 0, 0, 0);
        }
    }
    int cl = lane & 15, quad = lane >> 4;
    int p0 = rt * 16;
    int b = p0 >> 11, n0 = p0 & 2047;
    #pragma unroll
    for (int j = 0; j < 4; j++) {
        int o = cs * 64 + j * 16 + cl;
        float bb = b2[o];
        size_t base = (size_t)b * 128 * NPT + (size_t)o * NPT + n0 + quad * 4;
        float4 xv = *reinterpret_cast<const float4*>(xbf + base);
        float4 ov;
        ov.x = acc[j][0] + bb + xv.x;
        ov.y = acc[j][1] + bb + xv.y;
        ov.z = acc[j][2] + bb + xv.z;
        ov.w = acc[j][3] + bb + xv.w;
        *reinterpret_cast<float4*>(out + base) = ov;
    }
}

// ---------------------------------------------------------------------------
// Workspace layout (34,705,408 B; observed ws ≈ 268 MB):
//   0        qT 2MB [k1b->k3]    <- hbuf 4MB (k4b->k5f) aliases qT+kT
//   2097152  kT 2MB
//   4194304  vT 2MB
//   6291456  avT 2MB [k3->k3f]
//   8388608  xx 16KB
//   8404992  idxb 320KB
//   8732672  stats 2KB
//   8734720  b1p 2KB (pad)
//   8736768  Wbuf 128KB
//   8867840  wqFhi/lo wkFhi/lo wvFhi/lo 6x32KB
//   9064448  wcFhi 128KB | 9195520 wcFlo 128KB
//   9326592  w2Fhi 64KB  | 9392128 w2Flo 64KB
//   9457664  xhiF 1MB | 10506240 xloF 1MB
//   11554816 avFhi 1MB | 12603392 avFlo 1MB
//   13651968 hFhi 2MB  | 15749120 hFlo 2MB
//   17846272 key 16MB [k2a->k2b, reused per slab]
//   34623488 mutflag 80KB
// ---------------------------------------------------------------------------
#define WS_FULL 34705408u

extern "C" void kernel_launch(void* const* d_in, const int* in_sizes, int n_in,
                              void* d_out, int out_size, void* d_ws, size_t ws_size,
                              hipStream_t stream) {
    fp desc1 = (fp)d_in[0];
    fp wq = (fp)d_in[1];  fp bq = (fp)d_in[2];
    fp wk = (fp)d_in[3];  fp bk = (fp)d_in[4];
    fp wv = (fp)d_in[5];  fp bv = (fp)d_in[6];
    fp wm = (fp)d_in[7];  fp bm = (fp)d_in[8];
    fp w1 = (fp)d_in[9];  fp b1 = (fp)d_in[10];
    fp gamma = (fp)d_in[11]; fp beta = (fp)d_in[12];
    fp w2 = (fp)d_in[13]; fp b2 = (fp)d_in[14];

    if (ws_size < (size_t)WS_FULL) return;  // all-zero out => ws too small

    char* ws = (char*)d_ws;
    float*  qT    = (float*) (ws + 0);
    float*  kT    = (float*) (ws + 2097152);
    float*  vT    = (float*) (ws + 4194304);
    float*  avT   = (float*) (ws + 6291456);
    float*  xx    = (float*) (ws + 8388608);
    int*    idxb  = (int*)   (ws + 8404992);
    float*  stats = (float*) (ws + 8732672);
    float*  b1p   = (float*) (ws + 8734720);
    float*  Wbuf  = (float*) (ws + 8736768);
    ushort* wqFhi = (ushort*)(ws + 8867840);
    ushort* wqFlo = (ushort*)(ws + 8900608);
    ushort* wkFhi = (ushort*)(ws + 8933376);
    ushort* wkFlo = (ushort*)(ws + 8966144);
    ushort* wvFhi = (ushort*)(ws + 8998912);
    ushort* wvFlo = (ushort*)(ws + 9031680);
    ushort* wcFhi = (ushort*)(ws + 9064448);
    ushort* wcFlo = (ushort*)(ws + 9195520);
    ushort* w2Fhi = (ushort*)(ws + 9326592);
    ushort* w2Flo = (ushort*)(ws + 9392128);
    ushort* xhiF  = (ushort*)(ws + 9457664);
    ushort* xloF  = (ushort*)(ws + 10506240);
    ushort* avFhi = (ushort*)(ws + 11554816);
    ushort* avFlo = (ushort*)(ws + 12603392);
    ushort* hFhi  = (ushort*)(ws + 13651968);
    ushort* hFlo  = (ushort*)(ws + 15749120);
    float*  key   = (float*) (ws + 17846272);
    unsigned char* mutflag = (unsigned char*)(ws + 34623488);
    float*  hbuf  = (float*) (ws + 0);      // aliases qT+kT (dead after k3)

    prep1<<<130, 256, 0, stream>>>(w1, wm, bm, b1, Wbuf, b1p);
    prep2<<<578, 256, 0, stream>>>(wq, wk, wv, w1, Wbuf, w2,
                                   wqFhi, wqFlo, wkFhi, wkFlo, wvFhi, wvFlo,
                                   wcFhi, wcFlo, w2Fhi, w2Flo, stats);
    k1a_frag<<<256, 256, 0, stream>>>(desc1, xx, xhiF, xloF);
    k1b_qkv<<<384, 256, 0, stream>>>(xhiF, xloF, wqFhi, wqFlo, wkFhi, wkFlo,
                                     wvFhi, wvFlo, bq, bk, bv, qT, kT, vT);
    for (int s = 0; s < 2; s++) {
        k2a_gemm<<<1024, 256, 0, stream>>>(xhiF, xloF, xx, key, s * 2048);
        k2b_topk<<<512, 256, 0, stream>>>(key, idxb, s * 2048);
    }
    k2c_mutual<<<320, 256, 0, stream>>>(idxb, mutflag);
    k3_attn<<<2048, 256, 0, stream>>>(qT, kT, vT, idxb, mutflag, avT);
    fragify128<<<256, 256, 0, stream>>>(avT, avFhi, avFlo);
    k4b_h<<<256, 256, 0, stream>>>(xhiF, xloF, avFhi, avFlo, wcFhi, wcFlo,
                                   b1p, hbuf, stats);
    k5f_frag<<<256, 256, 0, stream>>>(hbuf, stats, gamma, beta, hFhi, hFlo);
    k5b_out<<<128, 256, 0, stream>>>(hFhi, hFlo, w2Fhi, w2Flo, b2, desc1,
                                     (float*)d_out);
}

// Round 10
// 201.714 us; speedup vs baseline: 1.5515x; 1.1635x over previous
//
#include <hip/hip_runtime.h>
#include <math.h>

#define NPT 2048
#define KNN 20

typedef const float* fp;
typedef __attribute__((ext_vector_type(4))) float f32x4;
typedef __attribute__((ext_vector_type(8))) short s16x8;

// round-to-nearest-even f32 -> bf16 bits (inputs are finite)
__device__ __forceinline__ ushort f2bf_rne(float v) {
    unsigned u = __float_as_uint(v);
    unsigned r = u + 0x7FFFu + ((u >> 16) & 1u);
    return (ushort)(r >> 16);
}
__device__ __forceinline__ float bfbits2f(ushort h) {
    return __uint_as_float(((unsigned)h) << 16);
}
__device__ __forceinline__ s16x8 ldfrag(const ushort* p) {
    union { uint4 u; s16x8 s; } cv;
    cv.u = *reinterpret_cast<const uint4*>(p);
    return cv.s;
}
// 8 consecutive f32 -> bf16 hi/lo fragment pair (in-register fragify)
__device__ __forceinline__ void f8_hilo(const float* row, s16x8* hi, s16x8* lo) {
    float4 f0 = *reinterpret_cast<const float4*>(row);
    float4 f1 = *reinterpret_cast<const float4*>(row + 4);
    float f[8] = {f0.x, f0.y, f0.z, f0.w, f1.x, f1.y, f1.z, f1.w};
    union { ushort u[8]; s16x8 s; } H, L;
    #pragma unroll
    for (int j = 0; j < 8; j++) {
        ushort h = f2bf_rne(f[j]);
        H.u[j] = h;
        L.u[j] = f2bf_rne(f[j] - bfbits2f(h));
    }
    *hi = H.s; *lo = L.s;
}

// ---------------------------------------------------------------------------
// prep_all: blocks [0,256) = k1a (fragify x + xx); blocks [256,835) =
//   weight frags (q/k/v K=128; wc=[w1x | w1a@wm] K=256 with on-the-fly W;
//   w2 K=256), b1p = b1 + w1a@bm, BN stats zero.
// Frag addressing: off = (nt*NKK + kk)*512 + lane*8 + j,
//   lane = (n&15)|(((k>>3)&3)<<4), j = k&7, kk = k>>5.
// ---------------------------------------------------------------------------
__global__ __launch_bounds__(256) void prep_all(
    fp xbf, fp wq, fp wk, fp wv, fp wm, fp w1, fp w2, fp bm, fp b1,
    float* xx, ushort* xhiF, ushort* xloF,
    ushort* wqFhi, ushort* wqFlo, ushort* wkFhi, ushort* wkFlo,
    ushort* wvFhi, ushort* wvFlo,
    ushort* wcFhi, ushort* wcFlo, ushort* w2Fhi, ushort* w2Flo,
    float* b1p, float* stats) {
    int t = threadIdx.x;
    if (blockIdx.x < 256) {                 // ---- k1a: x frags + xx ----
        __shared__ float xs[16][129];
        __shared__ float xpart[16][17];
        int p0 = blockIdx.x * 16;
        int b = p0 >> 11, n0 = p0 & 2047;
        fp xb = xbf + (size_t)b * 128 * NPT;
        {
            int c = t >> 1, half = t & 1;
            float4 f0 = *reinterpret_cast<const float4*>(xb + (size_t)c * NPT + n0 + half * 8);
            float4 f1 = *reinterpret_cast<const float4*>(xb + (size_t)c * NPT + n0 + half * 8 + 4);
            xs[half * 8 + 0][c] = f0.x; xs[half * 8 + 1][c] = f0.y;
            xs[half * 8 + 2][c] = f0.z; xs[half * 8 + 3][c] = f0.w;
            xs[half * 8 + 4][c] = f1.x; xs[half * 8 + 5][c] = f1.y;
            xs[half * 8 + 6][c] = f1.z; xs[half * 8 + 7][c] = f1.w;
        }
        __syncthreads();
        int p = t & 15, g = t >> 4, c0 = g * 8;
        float f[8];
        #pragma unroll
        for (int j = 0; j < 8; j++) f[j] = xs[p][c0 + j];
        float ps = 0.f;
        #pragma unroll
        for (int j = 0; j < 8; j++) ps += f[j] * f[j];
        xpart[p][g] = ps;
        union { ushort u[8]; uint4 q; } H, L;
        #pragma unroll
        for (int j = 0; j < 8; j++) {
            ushort hi = f2bf_rne(f[j]);
            H.u[j] = hi;
            L.u[j] = f2bf_rne(f[j] - bfbits2f(hi));
        }
        size_t off = ((size_t)blockIdx.x * 4 + (c0 >> 5)) * 512
                   + (size_t)(((((c0 >> 3) & 3) * 16) + p) * 8);
        *reinterpret_cast<uint4*>(xhiF + off) = H.q;
        *reinterpret_cast<uint4*>(xloF + off) = L.q;
        __syncthreads();
        if (t < 16) {
            float s = 0.f;
            #pragma unroll
            for (int gg = 0; gg < 16; gg++) s += xpart[t][gg];
            xx[p0 + t] = s;
        }
        return;
    }
    int wid = (blockIdx.x - 256) * 256 + t;
    if (wid < 49152) {                      // q/k/v frags (K=128)
        int which = wid >> 14, e = wid & 16383;
        int lane = (e >> 3) & 63, j = e & 7, kk = (e >> 9) & 3, nt = e >> 11;
        int n = nt * 16 + (lane & 15);
        int k = kk * 32 + (lane >> 4) * 8 + j;
        fp src = which == 0 ? wq : which == 1 ? wk : wv;
        float v = src[n * 128 + k];
        ushort hi = f2bf_rne(v);
        (which == 0 ? wqFhi : which == 1 ? wkFhi : wvFhi)[e] = hi;
        (which == 0 ? wqFlo : which == 1 ? wkFlo : wvFlo)[e] = f2bf_rne(v - bfbits2f(hi));
    } else if (wid < 114688) {              // wc frags (N=256, K=256)
        int e = wid - 49152;
        int j = e & 7, lane = (e >> 3) & 63, kk = (e >> 9) & 7, nt = e >> 12;
        int n = nt * 16 + (lane & 15);
        int k = kk * 32 + (lane >> 4) * 8 + j;
        float v;
        if (k < 128) {
            v = w1[n * 256 + k];
        } else {                            // W[n][k-128] = w1a@wm on the fly
            int c = k - 128;
            float s = 0.f;
            for (int i = 0; i < 128; i += 4) {
                float4 wr = *reinterpret_cast<const float4*>(w1 + n * 256 + 128 + i);
                s += wr.x * wm[(i + 0) * 128 + c];
                s += wr.y * wm[(i + 1) * 128 + c];
                s += wr.z * wm[(i + 2) * 128 + c];
                s += wr.w * wm[(i + 3) * 128 + c];
            }
            v = s;
        }
        ushort hi = f2bf_rne(v);
        wcFhi[e] = hi;
        wcFlo[e] = f2bf_rne(v - bfbits2f(hi));
    } else if (wid < 147456) {              // w2 frags (N=128, K=256)
        int e = wid - 114688;
        int j = e & 7, lane = (e >> 3) & 63, kk = (e >> 9) & 7, nt = e >> 12;
        int n = nt * 16 + (lane & 15);
        int k = kk * 32 + (lane >> 4) * 8 + j;
        float v = w2[n * 256 + k];
        ushort hi = f2bf_rne(v);
        w2Fhi[e] = hi;
        w2Flo[e] = f2bf_rne(v - bfbits2f(hi));
    } else if (wid < 147712) {              // b1p = b1 + w1a@bm
        int o = wid - 147456;
        float s = b1[o];
        for (int i = 0; i < 128; i++)
            s += w1[o * 256 + 128 + i] * bm[i];
        b1p[o] = s;
    } else {                                // BN stats zero (512)
        stats[wid - 147712] = 0.0f;
    }
}

// ---------------------------------------------------------------------------
// gemm_all: blocks [0,384) = qkv GEMM; [384,1408) = key GEMM slab 0;
//           [1408,2432) = key GEMM slab 1. All hi/lo bf16 MFMA.
// ---------------------------------------------------------------------------
__global__ __launch_bounds__(256) void gemm_all(
    const ushort* xhiF, const ushort* xloF, const float* xx,
    const ushort* wqFhi, const ushort* wqFlo,
    const ushort* wkFhi, const ushort* wkFlo,
    const ushort* wvFhi, const ushort* wvFlo,
    fp bq, fp bk, fp bv, float* qT, float* kT, float* vT,
    float* key0, float* key1) {
    int t = threadIdx.x, wvi = t >> 6, lane = t & 63;
    if (blockIdx.x < 384) {                 // ---- qkv ----
        int gw = blockIdx.x * 4 + wvi;      // 0..1535
        int rt = gw / 6, rem = gw - rt * 6;
        int mat = rem >> 1, hf = rem & 1;
        const ushort* whi = mat == 0 ? wqFhi : mat == 1 ? wkFhi : wvFhi;
        const ushort* wlo = mat == 0 ? wqFlo : mat == 1 ? wkFlo : wvFlo;
        fp bias    = mat == 0 ? bq : mat == 1 ? bk : bv;
        float* out = mat == 0 ? qT : mat == 1 ? kT : vT;
        f32x4 acc[4];
        #pragma unroll
        for (int j = 0; j < 4; j++) acc[j] = (f32x4){0.f, 0.f, 0.f, 0.f};
        for (int kk = 0; kk < 4; kk++) {
            s16x8 ahi = ldfrag(xhiF + ((size_t)(rt * 4 + kk)) * 512 + lane * 8);
            s16x8 alo = ldfrag(xloF + ((size_t)(rt * 4 + kk)) * 512 + lane * 8);
            #pragma unroll
            for (int j = 0; j < 4; j++) {
                int nt = hf * 4 + j;
                s16x8 bhi = ldfrag(whi + ((size_t)(nt * 4 + kk)) * 512 + lane * 8);
                s16x8 blo = ldfrag(wlo + ((size_t)(nt * 4 + kk)) * 512 + lane * 8);
                acc[j] = __builtin_amdgcn_mfma_f32_16x16x32_bf16(ahi, bhi, acc[j], 0, 0, 0);
                acc[j] = __builtin_amdgcn_mfma_f32_16x16x32_bf16(alo, bhi, acc[j], 0, 0, 0);
                acc[j] = __builtin_amdgcn_mfma_f32_16x16x32_bf16(ahi, blo, acc[j], 0, 0, 0);
            }
        }
        int cl = lane & 15, quad = lane >> 4, p0 = rt * 16;
        #pragma unroll
        for (int j = 0; j < 4; j++) {
            int o = hf * 64 + j * 16 + cl;
            float bvv = bias[o];
            #pragma unroll
            for (int r = 0; r < 4; r++)
                out[(size_t)(p0 + quad * 4 + r) * 128 + o] = acc[j][r] + bvv;
        }
        return;
    }
    // ---- key GEMM ----
    int slab = (blockIdx.x >= 1408) ? 1 : 0;
    int lb = blockIdx.x - 384 - slab * 1024;
    int gw = lb * 4 + wvi;                  // 0..4095
    int rtl = gw >> 5, cs = gw & 31;
    int b = slab;
    int rt = slab * 128 + rtl;
    float* key = slab ? key1 : key0;

    f32x4 acc[4];
    #pragma unroll
    for (int j = 0; j < 4; j++) acc[j] = (f32x4){0.f, 0.f, 0.f, 0.f};
    for (int kk = 0; kk < 4; kk++) {
        s16x8 ahi = ldfrag(xhiF + ((size_t)(rt * 4 + kk)) * 512 + lane * 8);
        s16x8 alo = ldfrag(xloF + ((size_t)(rt * 4 + kk)) * 512 + lane * 8);
        #pragma unroll
        for (int j = 0; j < 4; j++) {
            int ct = b * 128 + cs * 4 + j;
            s16x8 bhi = ldfrag(xhiF + ((size_t)(ct * 4 + kk)) * 512 + lane * 8);
            s16x8 blo = ldfrag(xloF + ((size_t)(ct * 4 + kk)) * 512 + lane * 8);
            acc[j] = __builtin_amdgcn_mfma_f32_16x16x32_bf16(ahi, bhi, acc[j], 0, 0, 0);
            acc[j] = __builtin_amdgcn_mfma_f32_16x16x32_bf16(alo, bhi, acc[j], 0, 0, 0);
            acc[j] = __builtin_amdgcn_mfma_f32_16x16x32_bf16(ahi, blo, acc[j], 0, 0, 0);
        }
    }
    int cl = lane & 15, quad = lane >> 4;
    #pragma unroll
    for (int j = 0; j < 4; j++) {
        int col = cs * 64 + j * 16 + cl;
        float xxv = xx[b * 2048 + col];
        #pragma unroll
        for (int r = 0; r < 4; r++)
            key[(size_t)(rtl * 16 + quad * 4 + r) * 2048 + col] = 2.0f * acc[j][r] - xxv;
    }
}

// ---------------------------------------------------------------------------
// k2b_all: per-row top-20, both slabs. Wave per row, register candidates.
// ---------------------------------------------------------------------------
#define MERGE(off) { float ov = __shfl_xor(bv, off); int oi = __shfl_xor(bi, off); \
                     if (ov > bv || (ov == bv && oi < bi)) { bv = ov; bi = oi; } }

__global__ __launch_bounds__(256) void k2b_all(
    const float* key0, const float* key1, int* idxbuf) {
    int t = threadIdx.x, wvi = t >> 6, lane = t & 63;
    int slab = blockIdx.x >> 9;
    int rowl = (blockIdx.x & 511) * 4 + wvi;
    const float* key = slab ? key1 : key0;
    int rowbase = slab * 2048;
    const float4* kr = reinterpret_cast<const float4*>(key + (size_t)rowl * 2048);
    float rv[32];
    #pragma unroll
    for (int j = 0; j < 8; j++) {
        float4 v = kr[j * 64 + lane];
        rv[j * 4 + 0] = v.x; rv[j * 4 + 1] = v.y;
        rv[j * 4 + 2] = v.z; rv[j * 4 + 3] = v.w;
    }
    unsigned removed = 0u;
    for (int iter = 0; iter < KNN; iter++) {
        float bv = -3.4e38f; int bi = 0;
        #pragma unroll
        for (int sl = 0; sl < 32; sl++) {
            bool live = ((removed >> sl) & 1u) == 0u;
            if (live && rv[sl] > bv) { bv = rv[sl]; bi = (sl >> 2) * 256 + lane * 4 + (sl & 3); }
        }
        MERGE(32) MERGE(16) MERGE(8) MERGE(4) MERGE(2) MERGE(1)
        bi &= 2047;
        if (lane == 0) idxbuf[(size_t)(rowbase + rowl) * KNN + iter] = bi;
        if (((bi >> 2) & 63) == lane) removed |= 1u << ((bi >> 8) * 4 + (bi & 3));
    }
}

// ---------------------------------------------------------------------------
// k3: sparse mutual-KNN attention, 2 points/block; mutuality scan inline
//     (lane j<20 scans neighbor row via 5 int4 loads), ballot-compacted.
// ---------------------------------------------------------------------------
__global__ __launch_bounds__(256) void k3_attn(
    fp qT, fp kT, fp vT, const int* idxbuf, float* avT) {
    __shared__ float sbuf[2][KNN * 4];
    __shared__ int   mlist[2][KNN];
    __shared__ int   cnt_s[2];
    int tt = threadIdx.x;
    int half = tt >> 7, t = tt & 127;
    int p = blockIdx.x * 2 + half;
    int b = p >> 11, n = p & 2047;
    int bbase = b * NPT;
    int h = t >> 5;

    if ((tt >> 6) == half * 2) {            // wave 0 of each half
        int lane = tt & 63;
        bool fl = false; int m = 0;
        if (lane < KNN) {
            m = idxbuf[(size_t)p * KNN + lane] & 2047;
            const int4* mrow = reinterpret_cast<const int4*>(idxbuf + (size_t)(bbase + m) * KNN);
            int4 r0 = mrow[0], r1 = mrow[1], r2 = mrow[2], r3 = mrow[3], r4 = mrow[4];
            fl = (r0.x == n) || (r0.y == n) || (r0.z == n) || (r0.w == n)
              || (r1.x == n) || (r1.y == n) || (r1.z == n) || (r1.w == n)
              || (r2.x == n) || (r2.y == n) || (r2.z == n) || (r2.w == n)
              || (r3.x == n) || (r3.y == n) || (r3.z == n) || (r3.w == n)
              || (r4.x == n) || (r4.y == n) || (r4.z == n) || (r4.w == n);
        }
        unsigned long long mask = __ballot(fl);
        int pos = __popcll(mask & ((1ull << lane) - 1ull));
        if (fl) mlist[half][pos] = m;
        if (lane == 0) cnt_s[half] = (int)__popcll(mask);
    }
    __syncthreads();

    int cnt = cnt_s[half];
    float qv = qT[(size_t)p * 128 + t];
    for (int jj = 0; jj < cnt; jj++) {
        int m = mlist[half][jj];
        float prod = qv * kT[(size_t)(bbase + m) * 128 + t];
        prod += __shfl_xor(prod, 16);
        prod += __shfl_xor(prod, 8);
        prod += __shfl_xor(prod, 4);
        prod += __shfl_xor(prod, 2);
        prod += __shfl_xor(prod, 1);
        if ((t & 31) == 0) sbuf[half][jj * 4 + h] = prod * 0.17677669529663687f;
    }
    __syncthreads();

    float mx = -3.4e38f;
    for (int j = 0; j < cnt; j++) mx = fmaxf(mx, sbuf[half][j * 4 + h]);
    float den = 0.f;
    for (int j = 0; j < cnt; j++) den += expf(sbuf[half][j * 4 + h] - mx);
    float inv = (cnt > 0) ? (1.0f / den) : 0.0f;
    float acc = 0.f;
    for (int j = 0; j < cnt; j++) {
        float pw = expf(sbuf[half][j * 4 + h] - mx) * inv;
        acc += pw * vT[(size_t)(bbase + mlist[half][j]) * 128 + t];
    }
    avT[(size_t)p * 128 + t] = acc;
}

// ---------------------------------------------------------------------------
// k4b: h = w1x@x + W@av + b1p via MFMA (K=256: x frags kk 0..3, av fragified
//      in-register from f32 kk 4..7). Epilogue: hbuf + wave-reduced BN stats.
// ---------------------------------------------------------------------------
__global__ __launch_bounds__(256) void k4b_h(
    const ushort* xhiF, const ushort* xloF, const float* avT,
    const ushort* wcFhi, const ushort* wcFlo,
    const float* b1p, float* hbuf, float* stats) {
    int t = threadIdx.x, cs = t >> 6, lane = t & 63;
    int rt = blockIdx.x;                    // 0..255
    int p0 = rt * 16;

    f32x4 acc[4];
    #pragma unroll
    for (int j = 0; j < 4; j++) acc[j] = (f32x4){0.f, 0.f, 0.f, 0.f};

    for (int kk = 0; kk < 8; kk++) {
        s16x8 ahi, alo;
        if (kk < 4) {
            ahi = ldfrag(xhiF + ((size_t)(rt * 4 + kk)) * 512 + lane * 8);
            alo = ldfrag(xloF + ((size_t)(rt * 4 + kk)) * 512 + lane * 8);
        } else {
            const float* arow = avT + (size_t)(p0 + (lane & 15)) * 128
                              + (kk - 4) * 32 + (lane >> 4) * 8;
            f8_hilo(arow, &ahi, &alo);
        }
        #pragma unroll
        for (int j = 0; j < 4; j++) {
            int nt = cs * 4 + j;
            s16x8 bhi = ldfrag(wcFhi + ((size_t)(nt * 8 + kk)) * 512 + lane * 8);
            s16x8 blo = ldfrag(wcFlo + ((size_t)(nt * 8 + kk)) * 512 + lane * 8);
            acc[j] = __builtin_amdgcn_mfma_f32_16x16x32_bf16(ahi, bhi, acc[j], 0, 0, 0);
            acc[j] = __builtin_amdgcn_mfma_f32_16x16x32_bf16(alo, bhi, acc[j], 0, 0, 0);
            acc[j] = __builtin_amdgcn_mfma_f32_16x16x32_bf16(ahi, blo, acc[j], 0, 0, 0);
        }
    }

    int cl = lane & 15, quad = lane >> 4;
    #pragma unroll
    for (int j = 0; j < 4; j++) {
        int o = cs * 64 + j * 16 + cl;
        float bb = b1p[o];
        float s = 0.f, s2 = 0.f;
        #pragma unroll
        for (int r = 0; r < 4; r++) {
            float v = acc[j][r] + bb;
            hbuf[(size_t)(p0 + quad * 4 + r) * 256 + o] = v;
            s += v; s2 += v * v;
        }
        s  += __shfl_xor(s, 16);  s  += __shfl_xor(s, 32);
        s2 += __shfl_xor(s2, 16); s2 += __shfl_xor(s2, 32);
        if (quad == 0) {
            atomicAdd(&stats[o], s);
            atomicAdd(&stats[256 + o], s2);
        }
    }
}

// ---------------------------------------------------------------------------
// k5b: out = w2@relu(BN(h)) + b2 + x via MFMA (K=256); BN+ReLU+hi/lo split
//      applied in-register per A-fragment. 256 blocks; wave = 32 out-chans.
// ---------------------------------------------------------------------------
__global__ __launch_bounds__(256) void k5b_out(
    const float* hbuf, const float* stats, fp gamma, fp beta,
    const ushort* w2Fhi, const ushort* w2Flo,
    fp b2, fp xbf, float* out) {
    int t = threadIdx.x, wvi = t >> 6, lane = t & 63;
    int rt = blockIdx.x;                    // 0..255
    int p0 = rt * 16;

    f32x4 acc[2];
    acc[0] = (f32x4){0.f, 0.f, 0.f, 0.f};
    acc[1] = (f32x4){0.f, 0.f, 0.f, 0.f};

    for (int kk = 0; kk < 8; kk++) {
        int c0 = kk * 32 + (lane >> 4) * 8;
        const float* hrow = hbuf + (size_t)(p0 + (lane & 15)) * 256 + c0;
        float4 f0 = *reinterpret_cast<const float4*>(hrow);
        float4 f1 = *reinterpret_cast<const float4*>(hrow + 4);
        float4 s0 = *reinterpret_cast<const float4*>(stats + c0);
        float4 s1 = *reinterpret_cast<const float4*>(stats + c0 + 4);
        float4 q0 = *reinterpret_cast<const float4*>(stats + 256 + c0);
        float4 q1 = *reinterpret_cast<const float4*>(stats + 256 + c0 + 4);
        float4 g0 = *reinterpret_cast<const float4*>(gamma + c0);
        float4 g1 = *reinterpret_cast<const float4*>(gamma + c0 + 4);
        float4 e0 = *reinterpret_cast<const float4*>(beta + c0);
        float4 e1 = *reinterpret_cast<const float4*>(beta + c0 + 4);
        float f[8] = {f0.x, f0.y, f0.z, f0.w, f1.x, f1.y, f1.z, f1.w};
        float sm[8] = {s0.x, s0.y, s0.z, s0.w, s1.x, s1.y, s1.z, s1.w};
        float sq[8] = {q0.x, q0.y, q0.z, q0.w, q1.x, q1.y, q1.z, q1.w};
        float gm[8] = {g0.x, g0.y, g0.z, g0.w, g1.x, g1.y, g1.z, g1.w};
        float bt[8] = {e0.x, e0.y, e0.z, e0.w, e1.x, e1.y, e1.z, e1.w};
        union { ushort u[8]; s16x8 s; } H, L;
        #pragma unroll
        for (int j = 0; j < 8; j++) {
            float mu  = sm[j] * (1.0f / 4096.0f);
            float var = fmaxf(sq[j] * (1.0f / 4096.0f) - mu * mu, 0.0f);
            float a    = gm[j] / sqrtf(var + 1e-5f);
            float cadd = bt[j] - mu * a;
            float v = fmaxf(f[j] * a + cadd, 0.0f);
            ushort hi = f2bf_rne(v);
            H.u[j] = hi;
            L.u[j] = f2bf_rne(v - bfbits2f(hi));
        }
        s16x8 ahi = H.s, alo = L.s;
        #pragma unroll
        for (int jj = 0; jj < 2; jj++) {
            int nt = wvi * 2 + jj;
            s16x8 bhi = ldfrag(w2Fhi + ((size_t)(nt * 8 + kk)) * 512 + lane * 8);
            s16x8 blo = ldfrag(w2Flo + ((size_t)(nt * 8 + kk)) * 512 + lane * 8);
            acc[jj] = __builtin_amdgcn_mfma_f32_16x16x32_bf16(ahi, bhi, acc[jj], 0, 0, 0);
            acc[jj] = __builtin_amdgcn_mfma_f32_16x16x32_bf16(alo, bhi, acc[jj], 0, 0, 0);
            acc[jj] = __builtin_amdgcn_mfma_f32_16x16x32_bf16(ahi, blo, acc[jj], 0, 0, 0);
        }
    }
    int cl = lane & 15, quad = lane >> 4;
    int b = p0 >> 11, n0 = p0 & 2047;
    #pragma unroll
    for (int jj = 0; jj < 2; jj++) {
        int o = (wvi * 2 + jj) * 16 + cl;
        float bb = b2[o];
        size_t base = (size_t)b * 128 * NPT + (size_t)o * NPT + n0 + quad * 4;
        float4 xv = *reinterpret_cast<const float4*>(xbf + base);
        float4 ov;
        ov.x = acc[jj][0] + bb + xv.x;
        ov.y = acc[jj][1] + bb + xv.y;
        ov.z = acc[jj][2] + bb + xv.z;
        ov.w = acc[jj][3] + bb + xv.w;
        *reinterpret_cast<float4*>(out + base) = ov;
    }
}

// ---------------------------------------------------------------------------
// Workspace layout (44,978,176 B; observed ws ≈ 268 MB):
//   0        qT 2MB [gemm->k3]   <- hbuf 4MB (k4b->k5b) aliases qT+kT
//   2097152  kT 2MB
//   4194304  vT 2MB
//   6291456  avT 2MB [k3->k4b]
//   8388608  xx 16KB
//   8404992  idxb 320KB
//   8732672  stats 2KB
//   8734720  b1p 2KB (1KB used)
//   8736768  wqFhi/lo wkFhi/lo wvFhi/lo 6x32KB
//   8933376  wcFhi 128KB | 9064448 wcFlo 128KB
//   9195520  w2Fhi 64KB  | 9261056 w2Flo 64KB
//   9326592  xhiF 1MB | 10375168 xloF 1MB
//   11423744 key0 16MB | 28200960 key1 16MB  (concurrent slabs)
// ---------------------------------------------------------------------------
#define WS_FULL 44978176u

extern "C" void kernel_launch(void* const* d_in, const int* in_sizes, int n_in,
                              void* d_out, int out_size, void* d_ws, size_t ws_size,
                              hipStream_t stream) {
    fp desc1 = (fp)d_in[0];
    fp wq = (fp)d_in[1];  fp bq = (fp)d_in[2];
    fp wk = (fp)d_in[3];  fp bk = (fp)d_in[4];
    fp wv = (fp)d_in[5];  fp bv = (fp)d_in[6];
    fp wm = (fp)d_in[7];  fp bm = (fp)d_in[8];
    fp w1 = (fp)d_in[9];  fp b1 = (fp)d_in[10];
    fp gamma = (fp)d_in[11]; fp beta = (fp)d_in[12];
    fp w2 = (fp)d_in[13]; fp b2 = (fp)d_in[14];

    if (ws_size < (size_t)WS_FULL) return;  // all-zero out => ws too small

    char* ws = (char*)d_ws;
    float*  qT    = (float*) (ws + 0);
    float*  kT    = (float*) (ws + 2097152);
    float*  vT    = (float*) (ws + 4194304);
    float*  avT   = (float*) (ws + 6291456);
    float*  xx    = (float*) (ws + 8388608);
    int*    idxb  = (int*)   (ws + 8404992);
    float*  stats = (float*) (ws + 8732672);
    float*  b1p   = (float*) (ws + 8734720);
    ushort* wqFhi = (ushort*)(ws + 8736768);
    ushort* wqFlo = (ushort*)(ws + 8769536);
    ushort* wkFhi = (ushort*)(ws + 8802304);
    ushort* wkFlo = (ushort*)(ws + 8835072);
    ushort* wvFhi = (ushort*)(ws + 8867840);
    ushort* wvFlo = (ushort*)(ws + 8900608);
    ushort* wcFhi = (ushort*)(ws + 8933376);
    ushort* wcFlo = (ushort*)(ws + 9064448);
    ushort* w2Fhi = (ushort*)(ws + 9195520);
    ushort* w2Flo = (ushort*)(ws + 9261056);
    ushort* xhiF  = (ushort*)(ws + 9326592);
    ushort* xloF  = (ushort*)(ws + 10375168);
    float*  key0  = (float*) (ws + 11423744);
    float*  key1  = (float*) (ws + 28200960);
    float*  hbuf  = (float*) (ws + 0);      // aliases qT+kT (dead after k3)

    prep_all<<<835, 256, 0, stream>>>(desc1, wq, wk, wv, wm, w1, w2, bm, b1,
                                      xx, xhiF, xloF,
                                      wqFhi, wqFlo, wkFhi, wkFlo, wvFhi, wvFlo,
                                      wcFhi, wcFlo, w2Fhi, w2Flo, b1p, stats);
    gemm_all<<<2432, 256, 0, stream>>>(xhiF, xloF, xx,
                                       wqFhi, wqFlo, wkFhi, wkFlo, wvFhi, wvFlo,
                                       bq, bk, bv, qT, kT, vT, key0, key1);
    k2b_all<<<1024, 256, 0, stream>>>(key0, key1, idxb);
    k3_attn<<<2048, 256, 0, stream>>>(qT, kT, vT, idxb, avT);
    k4b_h<<<256, 256, 0, stream>>>(xhiF, xloF, avT, wcFhi, wcFlo,
                                   b1p, hbuf, stats);
    k5b_out<<<256, 256, 0, stream>>>(hbuf, stats, gamma, beta, w2Fhi, w2Flo,
                                     b2, desc1, (float*)d_out);
}